// Round 17
// baseline (3856.321 us; speedup 1.0000x reference)
//
#include <hip/hip_runtime.h>
#include <cstdint>

constexpr int Nn = 60000;
constexpr int Ee = 240000;
constexpr int Hh = 256;
constexpr int Mm = 64;
constexpr int F1c = 12;
constexpr int Lc = 4;
constexpr int NLc = 3;
constexpr int Gc = 2000;
constexpr float EPSc = 1e-5f;
constexpr int NB = (Nn + 255) / 256;
constexpr int CSB = 256;   // colstats blocks

typedef _Float16 f16x8 __attribute__((ext_vector_type(8)));
typedef __attribute__((ext_vector_type(4))) float f32x4;
typedef __attribute__((ext_vector_type(4))) unsigned short u16x4;
typedef unsigned short ushortt;

__device__ __forceinline__ ushortt f2h(float f) {
    union { _Float16 h; ushortt u; } c; c.h = (_Float16)f; return c.u;
}
__device__ __forceinline__ float h2f(ushortt u) {
    union { _Float16 h; ushortt u; } c; c.u = u; return (float)c.h;
}

// ---------------- embedding -> fp16 ----------------
__global__ void embed_x_kernel(const int* __restrict__ xidx, const float* __restrict__ xtab,
                               ushortt* __restrict__ x) {
    int n = blockIdx.x;
    int c = threadIdx.x;
    __shared__ int idx[9];
    if (c < 9) idx[c] = xidx[n * 9 + c];
    __syncthreads();
    float s = 0.f;
#pragma unroll
    for (int j = 0; j < 9; j++) s += xtab[idx[j] * Hh + c];
    x[(size_t)n * Hh + c] = f2h(s);
}

__global__ void seg_bounds_kernel(const int* __restrict__ batch, int* __restrict__ gstart) {
    int g = blockIdx.x * 256 + threadIdx.x;
    if (g > Gc) return;
    if (g == Gc) { gstart[Gc] = Nn; return; }
    int lo = 0, hi = Nn;
    while (lo < hi) { int mid = (lo + hi) >> 1; if (batch[mid] < g) lo = mid + 1; else hi = mid; }
    gstart[g] = lo;
}

// ---------------- CSR build ----------------
__global__ void deg_hist_kernel(const int* __restrict__ ei, int* __restrict__ deg) {
    int e = blockIdx.x * 256 + threadIdx.x;
    if (e >= Ee) return;
    atomicAdd(&deg[ei[Ee + e]], 1);
}

__global__ void psum_block_kernel(const int* __restrict__ deg, int* __restrict__ iscan,
                                  int* __restrict__ bsum) {
    __shared__ int s[256];
    int t = threadIdx.x;
    int i = blockIdx.x * 256 + t;
    int v = (i < Nn) ? deg[i] : 0;
    s[t] = v;
    __syncthreads();
    for (int off = 1; off < 256; off <<= 1) {
        int add = (t >= off) ? s[t - off] : 0;
        __syncthreads();
        s[t] += add;
        __syncthreads();
    }
    if (i < Nn) iscan[i] = s[t];
    if (t == 255) bsum[blockIdx.x] = s[255];
}

__global__ void scan_bsum_kernel(const int* __restrict__ bsum, int* __restrict__ ebase,
                                 int* __restrict__ rowptr) {
    if (threadIdx.x != 0 || blockIdx.x != 0) return;
    int run = 0;
    for (int b = 0; b < NB; b++) { ebase[b] = run; run += bsum[b]; }
    rowptr[Nn] = Ee;
}

__global__ void finalize_rowptr_kernel(const int* __restrict__ deg, const int* __restrict__ iscan,
                                       const int* __restrict__ ebase, int* __restrict__ rowptr) {
    int i = blockIdx.x * 256 + threadIdx.x;
    if (i >= Nn) return;
    rowptr[i] = ebase[i >> 8] + iscan[i] - deg[i];
}

__global__ void fill_eid_kernel(const int* __restrict__ ei, int* __restrict__ cursor,
                                int* __restrict__ eid, int* __restrict__ esrc,
                                int* __restrict__ dstS) {
    int e = blockIdx.x * 256 + threadIdx.x;
    if (e >= Ee) return;
    int dst = ei[Ee + e];
    int pos = atomicAdd(&cursor[dst], 1);
    eid[pos] = e;
    esrc[pos] = ei[e];
    dstS[pos] = dst;
}

// ------- gather features into dst-sorted order, fp16 (once) -----------------------
template<int K>
__global__ void gather_feat_kernel(const float* __restrict__ F, const int* __restrict__ eid,
                                   ushortt* __restrict__ featS) {
    long i = (long)blockIdx.x * 256 + threadIdx.x;
    if (i >= (long)Ee * K) return;
    int e = (int)(i / K);
    int k = (int)(i % K);
    featS[i] = f2h(F[(size_t)eid[e] * K + k]);
}

// ------- weight f32->f16, fragment-coalesced layout [ks][col 256][32 packed] -------
__global__ void wconv_kernel(const float* __restrict__ src, ushortt* __restrict__ dst,
                             int nmat, int K, long dstMS, int kOff, long srcMS) {
    long idx = (long)blockIdx.x * 256 + threadIdx.x;
    long tot = (long)nmat * 256 * K;
    if (idx >= tot) return;
    int k = (int)(idx % K);
    long t = idx / K;
    int c = (int)(t & 255);
    int m = (int)(t >> 8);
    float w = src[m * srcMS + (long)k * 256 + c];
    int kg = kOff + k;
    int ks = kg >> 5;
    int k5 = kg & 31;
    int kpp = (((k5 & 15) >> 2) << 3) + (((k5 >> 4) & 1) << 2) + (k5 & 3);
    long o = m * dstMS + ((long)ks * 256 + c) * 32 + kpp;
    dst[o] = f2h(w);
}

// ---------------- Gram via LDS tiles ------------------------------------------------
template<int K>
__global__ void gram_kernel(const float* __restrict__ F, float* __restrict__ G,
                            float* __restrict__ s) {
    constexpr int NP = K * (K + 1) / 2;
    __shared__ float Ft[256 * K];
    int tid = threadIdx.x;
    int pi = 0, pj = 0;
    if (tid < NP) {
        int tt = tid;
        for (pi = 0; pi < K; pi++) { if (tt <= pi) { pj = tt; break; } tt -= (pi + 1); }
    }
    float acc = 0.f;
    int ntiles = (Ee + 255) / 256;
    for (int tile = blockIdx.x; tile < ntiles; tile += gridDim.x) {
        long r0 = (long)tile * 256;
        for (int idx = tid; idx < 256 * K; idx += 256) {
            long r = r0 + idx / K;
            Ft[idx] = (r < Ee) ? F[r * K + idx % K] : 0.f;
        }
        __syncthreads();
        if (tid < NP) {
            for (int r = 0; r < 256; r++) acc += Ft[r * K + pi] * Ft[r * K + pj];
        } else if (tid < NP + K) {
            int i = tid - NP;
            for (int r = 0; r < 256; r++) acc += Ft[r * K + i];
        }
        __syncthreads();
    }
    if (tid < NP) {
        atomicAdd(&G[pi * K + pj], acc);
        if (pi != pj) atomicAdd(&G[pj * K + pi], acc);
    } else if (tid < NP + K) {
        atomicAdd(&s[tid - NP], acc);
    }
}

// ------- setup: folded edge-BN affine per (layer, branch) --------------------------
__global__ void edge_bnparams_kernel(
    const float* __restrict__ G1, const float* __restrict__ s1,
    const float* __restrict__ G2, const float* __restrict__ s2,
    const float* __restrict__ f1_w1, const float* __restrict__ f1_b1,
    const float* __restrict__ f1_g, const float* __restrict__ f1_be,
    const float* __restrict__ f2_w1, const float* __restrict__ f2_b1,
    const float* __restrict__ f2_g, const float* __restrict__ f2_be,
    float Ecnt, float* __restrict__ scsAll, float* __restrict__ shsAll) {
    int lb = blockIdx.x;          // l*2 + br, 8 blocks
    int l = lb >> 1, br = lb & 1;
    int m = threadIdx.x;          // 64
    const float* G = br ? G2 : G1;
    const float* sv = br ? s2 : s1;
    int K = br ? 6 : F1c;
    const float* W  = br ? (f2_w1 + (size_t)l * 6 * Mm)   : (f1_w1 + (size_t)l * F1c * Mm);
    const float* bb = br ? (f2_b1 + l * Mm) : (f1_b1 + l * Mm);
    const float* gg = br ? (f2_g + l * Mm)  : (f1_g + l * Mm);
    const float* be = br ? (f2_be + l * Mm) : (f1_be + l * Mm);
    float wm[F1c];
    for (int i = 0; i < K; i++) wm[i] = W[i * Mm + m];
    float sw = 0.f;
    for (int i = 0; i < K; i++) sw += sv[i] * wm[i];
    float q = 0.f;
    for (int i = 0; i < K; i++) {
        float gi = 0.f;
        for (int j = 0; j < K; j++) gi += G[i * K + j] * wm[j];
        q += wm[i] * gi;
    }
    float rinv = 1.f / Ecnt;
    float colsum = sw + Ecnt * bb[m];
    float colsq = q + 2.f * bb[m] * sw + Ecnt * bb[m] * bb[m];
    float mu = colsum * rinv;
    float var = colsq * rinv - mu * mu;
    float rs = rsqrtf(var + EPSc) * gg[m];
    scsAll[lb * 64 + m] = rs;
    shsAll[lb * 64 + m] = bb[m] * rs + be[m] - mu * rs;
}

// ---------------- node BN stats: per-block partials (no atomics) -------------------
__global__ void colstats_part_kernel(const ushortt* __restrict__ A, long tot4,
                                     float* __restrict__ part) {
    __shared__ float ls[1024], lq[1024];
    int tid = threadIdx.x;
    long i0 = (long)blockIdx.x * 256 + tid;
    long stride = (long)gridDim.x * 256;
    float s[4] = {0, 0, 0, 0}, q[4] = {0, 0, 0, 0};
    for (long i = i0; i < tot4; i += stride) {
        u16x4 v = *(const u16x4*)(A + i * 4);
#pragma unroll
        for (int j = 0; j < 4; j++) { float f = h2f(v[j]); s[j] += f; q[j] += f * f; }
    }
#pragma unroll
    for (int j = 0; j < 4; j++) { ls[tid * 4 + j] = s[j]; lq[tid * 4 + j] = q[j]; }
    __syncthreads();
    if (tid < 64) {
#pragma unroll
        for (int j = 0; j < 4; j++) {
            float ts = ls[tid * 4 + j] + ls[(tid + 64) * 4 + j] +
                       ls[(tid + 128) * 4 + j] + ls[(tid + 192) * 4 + j];
            float tq = lq[tid * 4 + j] + lq[(tid + 64) * 4 + j] +
                       lq[(tid + 128) * 4 + j] + lq[(tid + 192) * 4 + j];
            part[(size_t)blockIdx.x * 512 + tid * 4 + j] = ts;
            part[(size_t)blockIdx.x * 512 + 256 + tid * 4 + j] = tq;
        }
    }
}

__global__ void colstats_reduce_kernel(const float* __restrict__ part,
                                       float* __restrict__ colsum, float* __restrict__ colsq) {
    int t = blockIdx.x * 256 + threadIdx.x;   // 0..511
    float acc = 0.f;
    for (int b = 0; b < CSB; b++) acc += part[(size_t)b * 512 + t];
    if (t < 256) colsum[t] = acc;
    else colsq[t - 256] = acc;
}

__global__ void bn_relu_h_kernel(const ushortt* __restrict__ A, ushortt* __restrict__ outp,
                                 const float* __restrict__ sum, const float* __restrict__ sq,
                                 const float* __restrict__ g, const float* __restrict__ be,
                                 float rinv, long tot4) {
    long i = (long)blockIdx.x * 256 + threadIdx.x;
    if (i >= tot4) return;
    int c0 = (int)((i * 4) & 255);
    u16x4 v = *(const u16x4*)(A + i * 4);
    u16x4 o;
#pragma unroll
    for (int j = 0; j < 4; j++) {
        int c = c0 + j;
        float m = sum[c] * rinv;
        float var = sq[c] * rinv - m * m;
        float f = (h2f(v[j]) - m) * rsqrtf(var + EPSc) * g[c] + be[c];
        o[j] = f2h(fmaxf(f, 0.f));
    }
    *(u16x4*)(outp + i * 4) = o;
}

// ---------------- fp16 MFMA GEMM v9: BK=64 per barrier round -----------------------
__global__ __launch_bounds__(256, 4) void bgemm_kernel(
    const void* __restrict__ A1v, int lda1, const ushortt* __restrict__ A2, int lda2,
    const ushortt* __restrict__ Wt,
    const float* __restrict__ bias, const ushortt* __restrict__ res,
    float* __restrict__ Cf, ushortt* __restrict__ Ch,
    int rows, int K1, int Ktot, int do_relu, int a1f32) {
    __shared__ char As[2][128 * 80];
    int tid = threadIdx.x;
    int lane = tid & 63;
    int wave = tid >> 6;
    int wrow0 = (wave >> 1) * 64;
    int wcol0 = (wave & 1) * 64;
    int r0 = blockIdx.y * 128;
    int j0 = blockIdx.x * 128;
    int l15 = lane & 15;
    int l4 = lane >> 4;

    int srow[4], sk4[4], soff[4];
#pragma unroll
    for (int p = 0; p < 4; p++) {
        int fid = p * 256 + tid;
        srow[p] = fid >> 3;
        sk4[p] = (fid & 7) * 4;
        soff[p] = srow[p] * 80 + ((((sk4[p] & 15) >> 2) << 4) + ((sk4[p] >> 4) << 3));
    }

    f32x4 acc[4][4];
#pragma unroll
    for (int i = 0; i < 4; i++)
#pragma unroll
        for (int j = 0; j < 4; j++) acc[i][j] = (f32x4){0.f, 0.f, 0.f, 0.f};

    for (int kt = 0; kt < Ktot; kt += 64) {
        const void* Av; int lda; int koff; int f32;
        if (kt < K1) { Av = A1v; lda = lda1; koff = kt; f32 = a1f32; }
        else         { Av = (const void*)A2; lda = lda2; koff = kt - K1; f32 = 0; }

        u16x4 hv[2][4];
        if (f32) {
#pragma unroll
            for (int h = 0; h < 2; h++)
#pragma unroll
                for (int p = 0; p < 4; p++) {
                    int rg = r0 + srow[p]; if (rg >= rows) rg = rows - 1;
                    float4 v = *(const float4*)((const float*)Av +
                        (size_t)rg * lda + koff + h * 32 + sk4[p]);
                    u16x4 hh;
                    hh[0] = f2h(v.x); hh[1] = f2h(v.y); hh[2] = f2h(v.z); hh[3] = f2h(v.w);
                    hv[h][p] = hh;
                }
        } else {
#pragma unroll
            for (int h = 0; h < 2; h++)
#pragma unroll
                for (int p = 0; p < 4; p++) {
                    int rg = r0 + srow[p]; if (rg >= rows) rg = rows - 1;
                    hv[h][p] = *(const u16x4*)((const ushortt*)Av +
                        (size_t)rg * lda + koff + h * 32 + sk4[p]);
                }
        }
        f16x8 bh[2][4];
#pragma unroll
        for (int h = 0; h < 2; h++) {
            long kb = ((long)((kt + h * 32) >> 5) * 256) * 32;
#pragma unroll
            for (int j = 0; j < 4; j++) {
                int colrow = j0 + wcol0 + j * 16 + l15;
                bh[h][j] = *(const f16x8*)(Wt + kb + (long)colrow * 32 + l4 * 8);
            }
        }
#pragma unroll
        for (int h = 0; h < 2; h++)
#pragma unroll
            for (int p = 0; p < 4; p++) *(u16x4*)(As[h] + soff[p]) = hv[h][p];
        __syncthreads();

#pragma unroll
        for (int h = 0; h < 2; h++) {
            f16x8 ah[4];
#pragma unroll
            for (int i = 0; i < 4; i++) {
                int row = wrow0 + i * 16 + l15;
                ah[i] = *(const f16x8*)(As[h] + row * 80 + l4 * 16);
            }
#pragma unroll
            for (int i = 0; i < 4; i++)
#pragma unroll
                for (int j = 0; j < 4; j++)
                    acc[i][j] = __builtin_amdgcn_mfma_f32_16x16x32_f16(ah[i], bh[h][j], acc[i][j], 0, 0, 0);
        }
        __syncthreads();
    }

#pragma unroll
    for (int i = 0; i < 4; i++) {
#pragma unroll
        for (int r = 0; r < 4; r++) {
            int row = r0 + wrow0 + i * 16 + l4 * 4 + r;
            if (row >= rows) continue;
#pragma unroll
            for (int j = 0; j < 4; j++) {
                int col = j0 + wcol0 + j * 16 + l15;
                float v = acc[i][j][r] + bias[col];
                if (do_relu) v = fmaxf(v, 0.f);
                if (res) v += h2f(res[(size_t)row * 256 + col]);
                if (Cf) Cf[(size_t)row * 256 + col] = v;
                if (Ch) Ch[(size_t)row * 256 + col] = f2h(v);
            }
        }
    }
}

// ------- agg init: zero rows for boundary (64-block straddling) / zero-deg nodes ---
__global__ __launch_bounds__(256) void agg_init_kernel(const int* __restrict__ rowptr,
                                                       float* __restrict__ agg) {
    int n = (blockIdx.x * 256 + threadIdx.x) >> 6;
    if (n >= Nn) return;
    int lane = threadIdx.x & 63;
    int rs = rowptr[n], re = rowptr[n + 1];
    bool need = (rs == re) || ((rs >> 6) != ((re - 1) >> 6));
    if (!need) return;
    f32x4 z = (f32x4){0.f, 0.f, 0.f, 0.f};
    *(f32x4*)(agg + (size_t)n * Hh + lane * 4) = z;
}

// ---------------- fused edge kernel + scatter:
//  w = relu((relu((featS@W1)*scs+shs))@W2 + b2); agg[dst] += w * xl[src]
//  128-edge tile x 128-col half; dst-sorted segmented reduction; direct store for
//  nodes fully inside a 64-edge block, fp32 atomicAdd for boundary nodes.
template<int K>
__global__ __launch_bounds__(256, 2) void edge_fused_kernel(
    const ushortt* __restrict__ featS, const float* __restrict__ W1,
    const float* __restrict__ scs, const float* __restrict__ shs,
    const ushortt* __restrict__ Wt, const float* __restrict__ bias,
    const int* __restrict__ rowptr, const int* __restrict__ esrcS,
    const int* __restrict__ dstS, const ushortt* __restrict__ xl,
    float* __restrict__ agg) {
    constexpr int KP = K + 1;
    __shared__ char As[2][128 * 80];
    __shared__ float Fs[128 * KP];
    __shared__ float W1s[K * 64];
    __shared__ float scsS[64], shsS[64];
    __shared__ ushortt wt[128 * 130];
    __shared__ int edstL[128], esrcL[128];
    int tid = threadIdx.x;
    int e0 = blockIdx.y * 128;
    for (int i = tid; i < K * 64; i += 256) W1s[i] = W1[i];
    if (tid < 64) { scsS[tid] = scs[tid]; shsS[tid] = shs[tid]; }
    if (tid < 128) {
        long e = (long)e0 + tid;
        if (e >= Ee) e = Ee - 1;
        edstL[tid] = dstS[e];
        esrcL[tid] = esrcS[e];
    }
    for (int idx = tid; idx < 128 * K; idx += 256) {
        int row = idx / K;
        int k = idx % K;
        long e = (long)e0 + row;
        if (e >= Ee) e = Ee - 1;
        Fs[row * KP + k] = h2f(featS[e * K + k]);
    }
    __syncthreads();
    // U = relu((f.W1)*scs+shs) into packed MFMA A layout
    {
        int row = tid >> 1;
        int m0 = (tid & 1) * 32;
        const float* fr = &Fs[row * KP];
#pragma unroll
        for (int mm = 0; mm < 32; mm++) {
            int m = m0 + mm;
            float u = 0.f;
#pragma unroll
            for (int k = 0; k < K; k++) u += fr[k] * W1s[k * 64 + m];
            float v = fmaxf(u * scsS[m] + shsS[m], 0.f);
            int k5 = m & 31;
            int kpp = (((k5 & 15) >> 2) << 3) + (((k5 >> 4) & 1) << 2) + (k5 & 3);
            *(ushortt*)(As[m >> 5] + row * 80 + kpp * 2) = f2h(v);
        }
    }
    __syncthreads();

    int lane = tid & 63;
    int wave = tid >> 6;
    int wrow0 = (wave >> 1) * 64;
    int wcol0 = (wave & 1) * 64;
    int j0 = blockIdx.x * 128;
    int l15 = lane & 15;
    int l4 = lane >> 4;

    f32x4 acc[4][4];
#pragma unroll
    for (int i = 0; i < 4; i++)
#pragma unroll
        for (int j = 0; j < 4; j++) acc[i][j] = (f32x4){0.f, 0.f, 0.f, 0.f};

#pragma unroll
    for (int kt = 0; kt < 64; kt += 32) {
        f16x8 bh[4];
        long kb = ((long)(kt >> 5) * 256) * 32;
#pragma unroll
        for (int j = 0; j < 4; j++) {
            int colrow = j0 + wcol0 + j * 16 + l15;
            bh[j] = *(const f16x8*)(Wt + kb + (long)colrow * 32 + l4 * 8);
        }
        f16x8 ah[4];
        const char* Az = As[kt >> 5];
#pragma unroll
        for (int i = 0; i < 4; i++) {
            int row = wrow0 + i * 16 + l15;
            ah[i] = *(const f16x8*)(Az + row * 80 + l4 * 16);
        }
#pragma unroll
        for (int i = 0; i < 4; i++)
#pragma unroll
            for (int j = 0; j < 4; j++)
                acc[i][j] = __builtin_amdgcn_mfma_f32_16x16x32_f16(ah[i], bh[j], acc[i][j], 0, 0, 0);
    }

    // w tile -> LDS (fp16, same rounding as the old Wc store)
#pragma unroll
    for (int i = 0; i < 4; i++)
#pragma unroll
        for (int r = 0; r < 4; r++) {
            int row = wrow0 + i * 16 + l4 * 4 + r;
#pragma unroll
            for (int j = 0; j < 4; j++) {
                int col = wcol0 + j * 16 + l15;
                float v = fmaxf(acc[i][j][r] + bias[j0 + col], 0.f);
                wt[row * 130 + col] = f2h(v);
            }
        }
    __syncthreads();

    // segmented reduction: thread = (col, 64-row half)
    int col = tid & 127;
    int rb = (tid >> 7) * 64;
    float run = 0.f;
    int prevd = -1;
    for (int r = rb; r < rb + 64; r++) {
        if (e0 + r >= Ee) break;
        int d = edstL[r];
        if (d != prevd) {
            if (prevd >= 0) {
                int rs = rowptr[prevd], re = rowptr[prevd + 1];
                float* ap = agg + (size_t)prevd * Hh + j0 + col;
                if ((rs >> 6) == ((re - 1) >> 6)) *ap = run;
                else atomicAdd(ap, run);
            }
            run = 0.f;
            prevd = d;
        }
        float w = h2f(wt[r * 130 + col]);
        float xv = h2f(xl[(size_t)esrcL[r] * Hh + j0 + col]);
        run += w * xv;
    }
    if (prevd >= 0) {
        int rs = rowptr[prevd], re = rowptr[prevd + 1];
        float* ap = agg + (size_t)prevd * Hh + j0 + col;
        if ((rs >> 6) == ((re - 1) >> 6)) *ap = run;
        else atomicAdd(ap, run);
    }
}

// ---------------- fused GraphNorm: one block per graph, segment in LDS -------------
__global__ __launch_bounds__(256) void gn_fused_kernel(
    const ushortt* __restrict__ h, const int* __restrict__ gstart,
    const float* __restrict__ ms, const float* __restrict__ w, const float* __restrict__ b,
    ushortt* __restrict__ outp) {
    __shared__ ushortt seg[128 * 256];
    int g = blockIdx.x;
    int c = threadIdx.x;
    int s = gstart[g], e = gstart[g + 1];
    int cnt = e - s;
    float cntf = (float)(cnt > 1 ? cnt : 1);
    float msc = ms[c], wc = w[c], bc = b[c];
    if (cnt <= 128) {
        float acc = 0.f;
        for (int n = 0; n < cnt; n++) {
            ushortt v = h[(size_t)(s + n) * Hh + c];
            seg[n * 256 + c] = v;
            acc += h2f(v);
        }
        float mean = acc / cntf;
        float sq = 0.f;
        for (int n = 0; n < cnt; n++) {
            ushortt ho = f2h(h2f(seg[n * 256 + c]) - msc * mean);
            seg[n * 256 + c] = ho;
            float o2 = h2f(ho);
            sq += o2 * o2;
        }
        float rstd = rsqrtf(sq / cntf + EPSc);
        for (int n = 0; n < cnt; n++) {
            float ov = h2f(seg[n * 256 + c]);
            outp[(size_t)(s + n) * Hh + c] = f2h(ov * rstd * wc + bc);
        }
    } else {
        float acc = 0.f;
        for (int n = s; n < e; n++) acc += h2f(h[(size_t)n * Hh + c]);
        float mean = acc / cntf;
        float sq = 0.f;
        for (int n = s; n < e; n++) {
            float ov = h2f(f2h(h2f(h[(size_t)n * Hh + c]) - msc * mean));
            sq += ov * ov;
        }
        float rstd = rsqrtf(sq / cntf + EPSc);
        for (int n = s; n < e; n++) {
            float ov = h2f(f2h(h2f(h[(size_t)n * Hh + c]) - msc * mean));
            outp[(size_t)n * Hh + c] = f2h(ov * rstd * wc + bc);
        }
    }
}

// =====================================================================================
extern "C" void kernel_launch(void* const* d_in, const int* in_sizes, int n_in,
                              void* d_out, int out_size, void* d_ws, size_t ws_size,
                              hipStream_t stream) {
    const int* x_idx      = (const int*)d_in[0];
    const int* edge_index = (const int*)d_in[2];
    const int* batch      = (const int*)d_in[3];
    const float* feature1 = (const float*)d_in[4];
    const float* feature2 = (const float*)d_in[5];
    const float* x_tab    = (const float*)d_in[6];
    const float* linx_w   = (const float*)d_in[8];
    const float* linx_b   = (const float*)d_in[9];
    const float* linx_g   = (const float*)d_in[10];
    const float* linx_be  = (const float*)d_in[11];
    const float* f1_w1    = (const float*)d_in[12];
    const float* f1_b1    = (const float*)d_in[13];
    const float* f1_g     = (const float*)d_in[14];
    const float* f1_be    = (const float*)d_in[15];
    const float* f1_w2    = (const float*)d_in[16];
    const float* f1_b2    = (const float*)d_in[17];
    const float* f2_w1    = (const float*)d_in[18];
    const float* f2_b1    = (const float*)d_in[19];
    const float* f2_g     = (const float*)d_in[20];
    const float* f2_be    = (const float*)d_in[21];
    const float* f2_w2    = (const float*)d_in[22];
    const float* f2_b2    = (const float*)d_in[23];
    const float* c1_rel_w  = (const float*)d_in[24];
    const float* c1_rel_b  = (const float*)d_in[25];
    const float* c1_root_w = (const float*)d_in[26];
    const float* c2_rel_w  = (const float*)d_in[27];
    const float* c2_rel_b  = (const float*)d_in[28];
    const float* c2_root_w = (const float*)d_in[29];
    const float* cat_w    = (const float*)d_in[30];
    const float* cat_b    = (const float*)d_in[31];
    const float* lins_w   = (const float*)d_in[32];
    const float* lins_b   = (const float*)d_in[33];
    const float* gn_w     = (const float*)d_in[34];
    const float* gn_b     = (const float*)d_in[35];
    const float* gn_ms    = (const float*)d_in[36];
    const float* fin_w    = (const float*)d_in[37];
    const float* fin_b    = (const float*)d_in[38];

    size_t NH = (size_t)Nn * Hh;
    char* p = (char*)d_ws;
    ushortt* X  = (ushortt*)p; p += NH * 2;
    ushortt* B1 = (ushortt*)p; p += NH * 2;
    ushortt* B2 = (ushortt*)p; p += NH * 2;
    ushortt* B3 = (ushortt*)p; p += NH * 2;
    // d_out doubles as fp32 agg scratch; fully rewritten by the final GEMM
    float* aggF = (float*)d_out;
    float* colsum = (float*)p; p += 256 * 4;
    float* colsq  = (float*)p; p += 256 * 4;
    float* part = (float*)p; p += (size_t)CSB * 512 * 4;
    float* G1 = (float*)p; p += 160 * 4;
    float* s1 = (float*)p; p += 16 * 4;
    float* G2 = (float*)p; p += 48 * 4;
    float* s2 = (float*)p; p += 16 * 4;
    float* scsAll = (float*)p; p += 8 * 64 * 4;
    float* shsAll = (float*)p; p += 8 * 64 * 4;
    int* gstart = (int*)p; p += 2048 * 4;
    int* deg    = (int*)p; p += Nn * 4;
    int* iscan  = (int*)p; p += Nn * 4;
    int* rowptr = (int*)p; p += (Nn + 256) * 4;
    int* cursor = (int*)p; p += Nn * 4;
    int* bsum   = (int*)p; p += 256 * 4;
    int* ebase  = (int*)p; p += 256 * 4;
    int* eid    = (int*)p; p += (size_t)Ee * 4;
    int* esrc   = (int*)p; p += (size_t)Ee * 4;
    int* dstS   = (int*)p; p += (size_t)Ee * 4;
    // dst-sorted fp16 edge features
    ushortt* featS1 = (ushortt*)p; p += (size_t)Ee * F1c * 2;
    ushortt* featS2 = (ushortt*)p; p += (size_t)Ee * 6 * 2;
    // fp16 weight buffers (fragment-coalesced)
    ushortt* linxW = (ushortt*)p; p += (size_t)4 * 65536 * 2;
    ushortt* convW = (ushortt*)p; p += (size_t)16 * 65536 * 2;
    ushortt* catW  = (ushortt*)p; p += (size_t)8 * 65536 * 2;
    ushortt* linsW = (ushortt*)p; p += (size_t)12 * 65536 * 2;
    ushortt* finW  = (ushortt*)p; p += (size_t)4 * 65536 * 2;
    ushortt* fw2W  = (ushortt*)p; p += (size_t)8 * 16384 * 2;

    long tot4 = (long)NH / 4;
    int blks4 = (int)((tot4 + 255) / 256);
    int blksE = (Ee + 255) / 256;
    int blksN = (Nn + 255) / 256;

    embed_x_kernel<<<Nn, 256, 0, stream>>>(x_idx, x_tab, X);
    seg_bounds_kernel<<<(Gc + 256) / 256, 256, 0, stream>>>(batch, gstart);
    hipMemsetAsync(deg, 0, Nn * sizeof(int), stream);
    deg_hist_kernel<<<blksE, 256, 0, stream>>>(edge_index, deg);
    psum_block_kernel<<<NB, 256, 0, stream>>>(deg, iscan, bsum);
    scan_bsum_kernel<<<1, 64, 0, stream>>>(bsum, ebase, rowptr);
    finalize_rowptr_kernel<<<blksN, 256, 0, stream>>>(deg, iscan, ebase, rowptr);
    hipMemcpyAsync(cursor, rowptr, Nn * sizeof(int), hipMemcpyDeviceToDevice, stream);
    fill_eid_kernel<<<blksE, 256, 0, stream>>>(edge_index, cursor, eid, esrc, dstS);
    gather_feat_kernel<F1c><<<(int)(((long)Ee * F1c + 255) / 256), 256, 0, stream>>>(
        feature1, eid, featS1);
    gather_feat_kernel<6><<<(int)(((long)Ee * 6 + 255) / 256), 256, 0, stream>>>(
        feature2, eid, featS2);

    hipMemsetAsync(G1, 0, 240 * sizeof(float), stream);
    gram_kernel<F1c><<<240, 256, 0, stream>>>(feature1, G1, s1);
    gram_kernel<6><<<240, 256, 0, stream>>>(feature2, G2, s2);
    edge_bnparams_kernel<<<8, 64, 0, stream>>>(G1, s1, G2, s2,
                                               f1_w1, f1_b1, f1_g, f1_be,
                                               f2_w1, f2_b1, f2_g, f2_be,
                                               (float)Ee, scsAll, shsAll);

    auto wcv = [&](const float* src, ushortt* dh, int nmat, int K,
                   long dstMS, int kOff, long srcMS) {
        long tot = (long)nmat * 256 * K;
        wconv_kernel<<<(int)((tot + 255) / 256), 256, 0, stream>>>(src, dh, nmat, K,
                                                                   dstMS, kOff, srcMS);
    };
    wcv(linx_w, linxW, 4, 256, 65536, 0, 65536);
    wcv(c1_rel_w,  convW,          4, 256, 262144, 0,   65536);
    wcv(c1_root_w, convW,          4, 256, 262144, 256, 65536);
    wcv(c2_rel_w,  convW + 131072, 4, 256, 262144, 0,   65536);
    wcv(c2_root_w, convW + 131072, 4, 256, 262144, 256, 65536);
    wcv(cat_w, catW, 4, 512, 131072, 0, 131072);
    wcv(lins_w, linsW, 12, 256, 65536, 0, 65536);
    wcv(fin_w, finW, 4, 256, 65536, 0, 65536);
    wcv(f1_w2, fw2W,         4, 64, 32768, 0, 16384);
    wcv(f2_w2, fw2W + 16384, 4, 64, 32768, 0, 16384);

    dim3 gN(2, (Nn + 127) / 128);   // x = col-half (fastest) -> A-row L2 reuse
    dim3 gE(2, (Ee + 127) / 128);

    for (int l = 0; l < Lc; l++) {
        // T = x @ linx_w + b -> B1 (fp16); xl = relu(BN(T)) -> X
        bgemm_kernel<<<gN, 256, 0, stream>>>(X, 256, nullptr, 0,
                                             linxW + (size_t)l * 65536,
                                             linx_b + l * Hh, nullptr, nullptr, B1,
                                             Nn, 256, 256, 0, 0);
        colstats_part_kernel<<<CSB, 256, 0, stream>>>(B1, tot4, part);
        colstats_reduce_kernel<<<2, 256, 0, stream>>>(part, colsum, colsq);
        bn_relu_h_kernel<<<blks4, 256, 0, stream>>>(B1, X, colsum, colsq,
                                                    linx_g + l * Hh, linx_be + l * Hh,
                                                    1.f / Nn, tot4);

        for (int br = 0; br < 2; br++) {
            const float* fw1 = br == 0 ? f1_w1 + (size_t)l * F1c * Mm : f2_w1 + (size_t)l * 6 * Mm;
            const float* fb2 = br == 0 ? f1_b2 + l * Hh : f2_b2 + l * Hh;
            const float* relb = br == 0 ? c1_rel_b + l * Hh : c2_rel_b + l * Hh;
            ushortt* fw2t = fw2W + (size_t)l * 32768 + (br ? 16384 : 0);
            ushortt* cvt  = convW + (size_t)l * 262144 + (br ? 131072 : 0);
            ushortt* hbr = br == 0 ? B3 : B2;
            const float* scsP = scsAll + (l * 2 + br) * 64;
            const float* shsP = shsAll + (l * 2 + br) * 64;

            // zero boundary / zero-degree rows, then fused edge GEMM + scatter
            agg_init_kernel<<<(Nn * 64 + 255) / 256, 256, 0, stream>>>(rowptr, aggF);
            if (br == 0)
                edge_fused_kernel<F1c><<<gE, 256, 0, stream>>>(
                    featS1, fw1, scsP, shsP, fw2t, fb2, rowptr, esrc, dstS, X, aggF);
            else
                edge_fused_kernel<6><<<gE, 256, 0, stream>>>(
                    featS2, fw1, scsP, shsP, fw2t, fb2, rowptr, esrc, dstS, X, aggF);

            // h_br = relu(agg(fp32) @ rel_w + xl @ root_w + rel_b)
            bgemm_kernel<<<gN, 256, 0, stream>>>(aggF, 256, X, 256, cvt,
                                                 relb, nullptr, nullptr, hbr,
                                                 Nn, 256, 512, 1, 1);
        }

        // h = relu([h1,h2] @ cat_w + cat_b) + xl -> B1
        bgemm_kernel<<<gN, 256, 0, stream>>>(B3, 256, B2, 256,
                                             catW + (size_t)l * 131072,
                                             cat_b + l * Hh, X, nullptr, B1,
                                             Nn, 256, 512, 1, 0);
        // residual linears: B1 <-> B2
        ushortt* cur = B1; ushortt* oth = B2;
        for (int k = 0; k < NLc; k++) {
            bgemm_kernel<<<gN, 256, 0, stream>>>(cur, 256, nullptr, 0,
                                                 linsW + ((size_t)l * NLc + k) * 65536,
                                                 lins_b + ((size_t)l * NLc + k) * Hh, cur,
                                                 nullptr, oth, Nn, 256, 256, 1, 0);
            ushortt* t = cur; cur = oth; oth = t;
        }
        // cur == B2. Fused GraphNorm: cur -> oth
        gn_fused_kernel<<<Gc, 256, 0, stream>>>(cur, gstart, gn_ms + l * Hh,
                                                gn_w + l * Hh, gn_b + l * Hh, oth);
        // x_next = h @ fin_w + fin_b
        bgemm_kernel<<<gN, 256, 0, stream>>>(oth, 256, nullptr, 0,
                                             finW + (size_t)l * 65536,
                                             fin_b + l * Hh, nullptr,
                                             (l == Lc - 1) ? (float*)d_out : nullptr,
                                             (l == Lc - 1) ? nullptr : X,
                                             Nn, 256, 256, 0, 0);
    }
}

// Round 18
// 2687.605 us; speedup vs baseline: 1.4349x; 1.4349x over previous
//
#include <hip/hip_runtime.h>
#include <cstdint>

constexpr int Nn = 60000;
constexpr int Ee = 240000;
constexpr int Hh = 256;
constexpr int Mm = 64;
constexpr int F1c = 12;
constexpr int Lc = 4;
constexpr int NLc = 3;
constexpr int Gc = 2000;
constexpr float EPSc = 1e-5f;
constexpr int NB = (Nn + 255) / 256;
constexpr int CSB = 256;   // colstats blocks

typedef _Float16 f16x8 __attribute__((ext_vector_type(8)));
typedef __attribute__((ext_vector_type(4))) float f32x4;
typedef __attribute__((ext_vector_type(4))) unsigned short u16x4;
typedef unsigned short ushortt;

__device__ __forceinline__ ushortt f2h(float f) {
    union { _Float16 h; ushortt u; } c; c.h = (_Float16)f; return c.u;
}
__device__ __forceinline__ float h2f(ushortt u) {
    union { _Float16 h; ushortt u; } c; c.u = u; return (float)c.h;
}

// ---------------- embedding -> fp16 ----------------
__global__ void embed_x_kernel(const int* __restrict__ xidx, const float* __restrict__ xtab,
                               ushortt* __restrict__ x) {
    int n = blockIdx.x;
    int c = threadIdx.x;
    __shared__ int idx[9];
    if (c < 9) idx[c] = xidx[n * 9 + c];
    __syncthreads();
    float s = 0.f;
#pragma unroll
    for (int j = 0; j < 9; j++) s += xtab[idx[j] * Hh + c];
    x[(size_t)n * Hh + c] = f2h(s);
}

__global__ void seg_bounds_kernel(const int* __restrict__ batch, int* __restrict__ gstart) {
    int g = blockIdx.x * 256 + threadIdx.x;
    if (g > Gc) return;
    if (g == Gc) { gstart[Gc] = Nn; return; }
    int lo = 0, hi = Nn;
    while (lo < hi) { int mid = (lo + hi) >> 1; if (batch[mid] < g) lo = mid + 1; else hi = mid; }
    gstart[g] = lo;
}

// ---------------- CSR build ----------------
__global__ void deg_hist_kernel(const int* __restrict__ ei, int* __restrict__ deg) {
    int e = blockIdx.x * 256 + threadIdx.x;
    if (e >= Ee) return;
    atomicAdd(&deg[ei[Ee + e]], 1);
}

__global__ void psum_block_kernel(const int* __restrict__ deg, int* __restrict__ iscan,
                                  int* __restrict__ bsum) {
    __shared__ int s[256];
    int t = threadIdx.x;
    int i = blockIdx.x * 256 + t;
    int v = (i < Nn) ? deg[i] : 0;
    s[t] = v;
    __syncthreads();
    for (int off = 1; off < 256; off <<= 1) {
        int add = (t >= off) ? s[t - off] : 0;
        __syncthreads();
        s[t] += add;
        __syncthreads();
    }
    if (i < Nn) iscan[i] = s[t];
    if (t == 255) bsum[blockIdx.x] = s[255];
}

__global__ void scan_bsum_kernel(const int* __restrict__ bsum, int* __restrict__ ebase,
                                 int* __restrict__ rowptr) {
    if (threadIdx.x != 0 || blockIdx.x != 0) return;
    int run = 0;
    for (int b = 0; b < NB; b++) { ebase[b] = run; run += bsum[b]; }
    rowptr[Nn] = Ee;
}

__global__ void finalize_rowptr_kernel(const int* __restrict__ deg, const int* __restrict__ iscan,
                                       const int* __restrict__ ebase, int* __restrict__ rowptr) {
    int i = blockIdx.x * 256 + threadIdx.x;
    if (i >= Nn) return;
    rowptr[i] = ebase[i >> 8] + iscan[i] - deg[i];
}

__global__ void fill_eid_kernel(const int* __restrict__ ei, int* __restrict__ cursor,
                                int* __restrict__ eid, int* __restrict__ esrc) {
    int e = blockIdx.x * 256 + threadIdx.x;
    if (e >= Ee) return;
    int dst = ei[Ee + e];
    int pos = atomicAdd(&cursor[dst], 1);
    eid[pos] = e;
    esrc[pos] = ei[e];
}

// ------- gather features into dst-sorted order, fp16 (once) -----------------------
template<int K>
__global__ void gather_feat_kernel(const float* __restrict__ F, const int* __restrict__ eid,
                                   ushortt* __restrict__ featS) {
    long i = (long)blockIdx.x * 256 + threadIdx.x;
    if (i >= (long)Ee * K) return;
    int e = (int)(i / K);
    int k = (int)(i % K);
    featS[i] = f2h(F[(size_t)eid[e] * K + k]);
}

// ------- weight f32->f16, fragment-coalesced layout [ks][col 256][32 packed] -------
__global__ void wconv_kernel(const float* __restrict__ src, ushortt* __restrict__ dst,
                             int nmat, int K, long dstMS, int kOff, long srcMS) {
    long idx = (long)blockIdx.x * 256 + threadIdx.x;
    long tot = (long)nmat * 256 * K;
    if (idx >= tot) return;
    int k = (int)(idx % K);
    long t = idx / K;
    int c = (int)(t & 255);
    int m = (int)(t >> 8);
    float w = src[m * srcMS + (long)k * 256 + c];
    int kg = kOff + k;
    int ks = kg >> 5;
    int k5 = kg & 31;
    int kpp = (((k5 & 15) >> 2) << 3) + (((k5 >> 4) & 1) << 2) + (k5 & 3);
    long o = m * dstMS + ((long)ks * 256 + c) * 32 + kpp;
    dst[o] = f2h(w);
}

// ---------------- Gram via LDS tiles ------------------------------------------------
template<int K>
__global__ void gram_kernel(const float* __restrict__ F, float* __restrict__ G,
                            float* __restrict__ s) {
    constexpr int NP = K * (K + 1) / 2;
    __shared__ float Ft[256 * K];
    int tid = threadIdx.x;
    int pi = 0, pj = 0;
    if (tid < NP) {
        int tt = tid;
        for (pi = 0; pi < K; pi++) { if (tt <= pi) { pj = tt; break; } tt -= (pi + 1); }
    }
    float acc = 0.f;
    int ntiles = (Ee + 255) / 256;
    for (int tile = blockIdx.x; tile < ntiles; tile += gridDim.x) {
        long r0 = (long)tile * 256;
        for (int idx = tid; idx < 256 * K; idx += 256) {
            long r = r0 + idx / K;
            Ft[idx] = (r < Ee) ? F[r * K + idx % K] : 0.f;
        }
        __syncthreads();
        if (tid < NP) {
            for (int r = 0; r < 256; r++) acc += Ft[r * K + pi] * Ft[r * K + pj];
        } else if (tid < NP + K) {
            int i = tid - NP;
            for (int r = 0; r < 256; r++) acc += Ft[r * K + i];
        }
        __syncthreads();
    }
    if (tid < NP) {
        atomicAdd(&G[pi * K + pj], acc);
        if (pi != pj) atomicAdd(&G[pj * K + pi], acc);
    } else if (tid < NP + K) {
        atomicAdd(&s[tid - NP], acc);
    }
}

// ------- setup: folded edge-BN affine per (layer, branch) --------------------------
__global__ void edge_bnparams_kernel(
    const float* __restrict__ G1, const float* __restrict__ s1,
    const float* __restrict__ G2, const float* __restrict__ s2,
    const float* __restrict__ f1_w1, const float* __restrict__ f1_b1,
    const float* __restrict__ f1_g, const float* __restrict__ f1_be,
    const float* __restrict__ f2_w1, const float* __restrict__ f2_b1,
    const float* __restrict__ f2_g, const float* __restrict__ f2_be,
    float Ecnt, float* __restrict__ scsAll, float* __restrict__ shsAll) {
    int lb = blockIdx.x;          // l*2 + br, 8 blocks
    int l = lb >> 1, br = lb & 1;
    int m = threadIdx.x;          // 64
    const float* G = br ? G2 : G1;
    const float* sv = br ? s2 : s1;
    int K = br ? 6 : F1c;
    const float* W  = br ? (f2_w1 + (size_t)l * 6 * Mm)   : (f1_w1 + (size_t)l * F1c * Mm);
    const float* bb = br ? (f2_b1 + l * Mm) : (f1_b1 + l * Mm);
    const float* gg = br ? (f2_g + l * Mm)  : (f1_g + l * Mm);
    const float* be = br ? (f2_be + l * Mm) : (f1_be + l * Mm);
    float wm[F1c];
    for (int i = 0; i < K; i++) wm[i] = W[i * Mm + m];
    float sw = 0.f;
    for (int i = 0; i < K; i++) sw += sv[i] * wm[i];
    float q = 0.f;
    for (int i = 0; i < K; i++) {
        float gi = 0.f;
        for (int j = 0; j < K; j++) gi += G[i * K + j] * wm[j];
        q += wm[i] * gi;
    }
    float rinv = 1.f / Ecnt;
    float colsum = sw + Ecnt * bb[m];
    float colsq = q + 2.f * bb[m] * sw + Ecnt * bb[m] * bb[m];
    float mu = colsum * rinv;
    float var = colsq * rinv - mu * mu;
    float rs = rsqrtf(var + EPSc) * gg[m];
    scsAll[lb * 64 + m] = rs;
    shsAll[lb * 64 + m] = bb[m] * rs + be[m] - mu * rs;
}

// ---------------- node BN stats: per-block partials (no atomics) -------------------
__global__ void colstats_part_kernel(const ushortt* __restrict__ A, long tot4,
                                     float* __restrict__ part) {
    __shared__ float ls[1024], lq[1024];
    int tid = threadIdx.x;
    long i0 = (long)blockIdx.x * 256 + tid;
    long stride = (long)gridDim.x * 256;
    float s[4] = {0, 0, 0, 0}, q[4] = {0, 0, 0, 0};
    for (long i = i0; i < tot4; i += stride) {
        u16x4 v = *(const u16x4*)(A + i * 4);
#pragma unroll
        for (int j = 0; j < 4; j++) { float f = h2f(v[j]); s[j] += f; q[j] += f * f; }
    }
#pragma unroll
    for (int j = 0; j < 4; j++) { ls[tid * 4 + j] = s[j]; lq[tid * 4 + j] = q[j]; }
    __syncthreads();
    if (tid < 64) {
#pragma unroll
        for (int j = 0; j < 4; j++) {
            float ts = ls[tid * 4 + j] + ls[(tid + 64) * 4 + j] +
                       ls[(tid + 128) * 4 + j] + ls[(tid + 192) * 4 + j];
            float tq = lq[tid * 4 + j] + lq[(tid + 64) * 4 + j] +
                       lq[(tid + 128) * 4 + j] + lq[(tid + 192) * 4 + j];
            part[(size_t)blockIdx.x * 512 + tid * 4 + j] = ts;
            part[(size_t)blockIdx.x * 512 + 256 + tid * 4 + j] = tq;
        }
    }
}

__global__ void colstats_reduce_kernel(const float* __restrict__ part,
                                       float* __restrict__ colsum, float* __restrict__ colsq) {
    int t = blockIdx.x * 256 + threadIdx.x;   // 0..511
    float acc = 0.f;
    for (int b = 0; b < CSB; b++) acc += part[(size_t)b * 512 + t];
    if (t < 256) colsum[t] = acc;
    else colsq[t - 256] = acc;
}

__global__ void bn_relu_h_kernel(const ushortt* __restrict__ A, ushortt* __restrict__ outp,
                                 const float* __restrict__ sum, const float* __restrict__ sq,
                                 const float* __restrict__ g, const float* __restrict__ be,
                                 float rinv, long tot4) {
    long i = (long)blockIdx.x * 256 + threadIdx.x;
    if (i >= tot4) return;
    int c0 = (int)((i * 4) & 255);
    u16x4 v = *(const u16x4*)(A + i * 4);
    u16x4 o;
#pragma unroll
    for (int j = 0; j < 4; j++) {
        int c = c0 + j;
        float m = sum[c] * rinv;
        float var = sq[c] * rinv - m * m;
        float f = (h2f(v[j]) - m) * rsqrtf(var + EPSc) * g[c] + be[c];
        o[j] = f2h(fmaxf(f, 0.f));
    }
    *(u16x4*)(outp + i * 4) = o;
}

// ---------------- fp16 MFMA GEMM v9: BK=64 per barrier round -----------------------
__global__ __launch_bounds__(256, 4) void bgemm_kernel(
    const void* __restrict__ A1v, int lda1, const ushortt* __restrict__ A2, int lda2,
    const ushortt* __restrict__ Wt,
    const float* __restrict__ bias, const ushortt* __restrict__ res,
    float* __restrict__ Cf, ushortt* __restrict__ Ch,
    int rows, int K1, int Ktot, int do_relu, int a1f32) {
    __shared__ char As[2][128 * 80];
    int tid = threadIdx.x;
    int lane = tid & 63;
    int wave = tid >> 6;
    int wrow0 = (wave >> 1) * 64;
    int wcol0 = (wave & 1) * 64;
    int r0 = blockIdx.y * 128;
    int j0 = blockIdx.x * 128;
    int l15 = lane & 15;
    int l4 = lane >> 4;

    int srow[4], sk4[4], soff[4];
#pragma unroll
    for (int p = 0; p < 4; p++) {
        int fid = p * 256 + tid;
        srow[p] = fid >> 3;
        sk4[p] = (fid & 7) * 4;
        soff[p] = srow[p] * 80 + ((((sk4[p] & 15) >> 2) << 4) + ((sk4[p] >> 4) << 3));
    }

    f32x4 acc[4][4];
#pragma unroll
    for (int i = 0; i < 4; i++)
#pragma unroll
        for (int j = 0; j < 4; j++) acc[i][j] = (f32x4){0.f, 0.f, 0.f, 0.f};

    for (int kt = 0; kt < Ktot; kt += 64) {
        const void* Av; int lda; int koff; int f32;
        if (kt < K1) { Av = A1v; lda = lda1; koff = kt; f32 = a1f32; }
        else         { Av = (const void*)A2; lda = lda2; koff = kt - K1; f32 = 0; }

        u16x4 hv[2][4];
        if (f32) {
#pragma unroll
            for (int h = 0; h < 2; h++)
#pragma unroll
                for (int p = 0; p < 4; p++) {
                    int rg = r0 + srow[p]; if (rg >= rows) rg = rows - 1;
                    float4 v = *(const float4*)((const float*)Av +
                        (size_t)rg * lda + koff + h * 32 + sk4[p]);
                    u16x4 hh;
                    hh[0] = f2h(v.x); hh[1] = f2h(v.y); hh[2] = f2h(v.z); hh[3] = f2h(v.w);
                    hv[h][p] = hh;
                }
        } else {
#pragma unroll
            for (int h = 0; h < 2; h++)
#pragma unroll
                for (int p = 0; p < 4; p++) {
                    int rg = r0 + srow[p]; if (rg >= rows) rg = rows - 1;
                    hv[h][p] = *(const u16x4*)((const ushortt*)Av +
                        (size_t)rg * lda + koff + h * 32 + sk4[p]);
                }
        }
        f16x8 bh[2][4];
#pragma unroll
        for (int h = 0; h < 2; h++) {
            long kb = ((long)((kt + h * 32) >> 5) * 256) * 32;
#pragma unroll
            for (int j = 0; j < 4; j++) {
                int colrow = j0 + wcol0 + j * 16 + l15;
                bh[h][j] = *(const f16x8*)(Wt + kb + (long)colrow * 32 + l4 * 8);
            }
        }
#pragma unroll
        for (int h = 0; h < 2; h++)
#pragma unroll
            for (int p = 0; p < 4; p++) *(u16x4*)(As[h] + soff[p]) = hv[h][p];
        __syncthreads();

#pragma unroll
        for (int h = 0; h < 2; h++) {
            f16x8 ah[4];
#pragma unroll
            for (int i = 0; i < 4; i++) {
                int row = wrow0 + i * 16 + l15;
                ah[i] = *(const f16x8*)(As[h] + row * 80 + l4 * 16);
            }
#pragma unroll
            for (int i = 0; i < 4; i++)
#pragma unroll
                for (int j = 0; j < 4; j++)
                    acc[i][j] = __builtin_amdgcn_mfma_f32_16x16x32_f16(ah[i], bh[h][j], acc[i][j], 0, 0, 0);
        }
        __syncthreads();
    }

#pragma unroll
    for (int i = 0; i < 4; i++) {
#pragma unroll
        for (int r = 0; r < 4; r++) {
            int row = r0 + wrow0 + i * 16 + l4 * 4 + r;
            if (row >= rows) continue;
#pragma unroll
            for (int j = 0; j < 4; j++) {
                int col = j0 + wcol0 + j * 16 + l15;
                float v = acc[i][j][r] + bias[col];
                if (do_relu) v = fmaxf(v, 0.f);
                if (res) v += h2f(res[(size_t)row * 256 + col]);
                if (Cf) Cf[(size_t)row * 256 + col] = v;
                if (Ch) Ch[(size_t)row * 256 + col] = f2h(v);
            }
        }
    }
}

// ---------------- fused edge kernel: U = relu((featS@W1)*scs+shs); Wc = relu(U@W2+b2)
template<int K>
__global__ __launch_bounds__(256, 4) void edge_gemm_kernel(
    const ushortt* __restrict__ featS, const float* __restrict__ W1,
    const float* __restrict__ scs, const float* __restrict__ shs,
    const ushortt* __restrict__ Wt, const float* __restrict__ bias,
    ushortt* __restrict__ Wc, int c0, int ec) {
    constexpr int KP = K + 1;          // pad: stride coprime with 32 banks
    __shared__ char As[2][128 * 80];
    __shared__ float Fs[128 * KP];
    __shared__ float W1s[K * 64];
    __shared__ float scsS[64], shsS[64];
    int tid = threadIdx.x;
    for (int i = tid; i < K * 64; i += 256) W1s[i] = W1[i];
    if (tid < 64) { scsS[tid] = scs[tid]; shsS[tid] = shs[tid]; }
    int r0 = blockIdx.y * 128;
    for (int idx = tid; idx < 128 * K; idx += 256) {
        int row = idx / K;
        int k = idx % K;
        long e = (long)c0 + r0 + row;
        if (e >= Ee) e = Ee - 1;
        Fs[row * KP + k] = h2f(featS[e * K + k]);
    }
    __syncthreads();
    {
        int row = tid >> 1;
        int m0 = (tid & 1) * 32;
        const float* fr = &Fs[row * KP];
#pragma unroll
        for (int mm = 0; mm < 32; mm++) {
            int m = m0 + mm;
            float u = 0.f;
#pragma unroll
            for (int k = 0; k < K; k++) u += fr[k] * W1s[k * 64 + m];
            float v = fmaxf(u * scsS[m] + shsS[m], 0.f);
            int k5 = m & 31;
            int kpp = (((k5 & 15) >> 2) << 3) + (((k5 >> 4) & 1) << 2) + (k5 & 3);
            *(ushortt*)(As[m >> 5] + row * 80 + kpp * 2) = f2h(v);
        }
    }
    __syncthreads();

    int lane = tid & 63;
    int wave = tid >> 6;
    int wrow0 = (wave >> 1) * 64;
    int wcol0 = (wave & 1) * 64;
    int j0 = blockIdx.x * 128;
    int l15 = lane & 15;
    int l4 = lane >> 4;

    f32x4 acc[4][4];
#pragma unroll
    for (int i = 0; i < 4; i++)
#pragma unroll
        for (int j = 0; j < 4; j++) acc[i][j] = (f32x4){0.f, 0.f, 0.f, 0.f};

#pragma unroll
    for (int kt = 0; kt < 64; kt += 32) {
        f16x8 bh[4];
        long kb = ((long)(kt >> 5) * 256) * 32;
#pragma unroll
        for (int j = 0; j < 4; j++) {
            int colrow = j0 + wcol0 + j * 16 + l15;
            bh[j] = *(const f16x8*)(Wt + kb + (long)colrow * 32 + l4 * 8);
        }
        f16x8 ah[4];
        const char* Az = As[kt >> 5];
#pragma unroll
        for (int i = 0; i < 4; i++) {
            int row = wrow0 + i * 16 + l15;
            ah[i] = *(const f16x8*)(Az + row * 80 + l4 * 16);
        }
#pragma unroll
        for (int i = 0; i < 4; i++)
#pragma unroll
            for (int j = 0; j < 4; j++)
                acc[i][j] = __builtin_amdgcn_mfma_f32_16x16x32_f16(ah[i], bh[j], acc[i][j], 0, 0, 0);
    }

#pragma unroll
    for (int i = 0; i < 4; i++) {
#pragma unroll
        for (int r = 0; r < 4; r++) {
            int row = wrow0 + i * 16 + l4 * 4 + r;
            if (r0 + row >= ec) continue;
#pragma unroll
            for (int j = 0; j < 4; j++) {
                int col = j0 + wcol0 + j * 16 + l15;
                float v = fmaxf(acc[i][j][r] + bias[col], 0.f);
                Wc[(size_t)(r0 + row) * 256 + col] = f2h(v);
            }
        }
    }
}

// ------- gather-aggregate (fp16 Wc, fp16 xl; fp32 reg acc) -------------------------
__global__ __launch_bounds__(256) void gather_agg_kernel(
    const int* __restrict__ rowptr, const int* __restrict__ esrc,
    const ushortt* __restrict__ Wc, const ushortt* __restrict__ xl,
    float* __restrict__ agg, ushortt* __restrict__ out16, int c0, int c1, int first) {
    int n = (blockIdx.x * 256 + threadIdx.x) >> 6;
    if (n >= Nn) return;
    int lane = threadIdx.x & 63;
    int rs = rowptr[n], re = rowptr[n + 1];
    if (rs < c0) rs = c0;
    if (re > c1) re = c1;
    float4 acc;
    if (out16 || first) {
        acc = make_float4(0.f, 0.f, 0.f, 0.f);
    } else {
        if (rs >= re) return;
        acc = *(float4*)(agg + (size_t)n * Hh + lane * 4);
    }
    for (int i = rs; i < re; i++) {
        u16x4 wv = *(const u16x4*)(Wc + (size_t)(i - c0) * Hh + lane * 4);
        u16x4 xv = *(const u16x4*)(xl + (size_t)esrc[i] * Hh + lane * 4);
        acc.x += h2f(wv[0]) * h2f(xv[0]);
        acc.y += h2f(wv[1]) * h2f(xv[1]);
        acc.z += h2f(wv[2]) * h2f(xv[2]);
        acc.w += h2f(wv[3]) * h2f(xv[3]);
    }
    if (out16) {
        u16x4 o;
        o[0] = f2h(acc.x); o[1] = f2h(acc.y); o[2] = f2h(acc.z); o[3] = f2h(acc.w);
        *(u16x4*)(out16 + (size_t)n * Hh + lane * 4) = o;
    } else {
        *(float4*)(agg + (size_t)n * Hh + lane * 4) = acc;
    }
}

// ---------------- fused GraphNorm: one block per graph, segment in LDS -------------
__global__ __launch_bounds__(256) void gn_fused_kernel(
    const ushortt* __restrict__ h, const int* __restrict__ gstart,
    const float* __restrict__ ms, const float* __restrict__ w, const float* __restrict__ b,
    ushortt* __restrict__ outp) {
    __shared__ ushortt seg[128 * 256];
    int g = blockIdx.x;
    int c = threadIdx.x;
    int s = gstart[g], e = gstart[g + 1];
    int cnt = e - s;
    float cntf = (float)(cnt > 1 ? cnt : 1);
    float msc = ms[c], wc = w[c], bc = b[c];
    if (cnt <= 128) {
        float acc = 0.f;
        for (int n = 0; n < cnt; n++) {
            ushortt v = h[(size_t)(s + n) * Hh + c];
            seg[n * 256 + c] = v;
            acc += h2f(v);
        }
        float mean = acc / cntf;
        float sq = 0.f;
        for (int n = 0; n < cnt; n++) {
            ushortt ho = f2h(h2f(seg[n * 256 + c]) - msc * mean);
            seg[n * 256 + c] = ho;
            float o2 = h2f(ho);
            sq += o2 * o2;
        }
        float rstd = rsqrtf(sq / cntf + EPSc);
        for (int n = 0; n < cnt; n++) {
            float ov = h2f(seg[n * 256 + c]);
            outp[(size_t)(s + n) * Hh + c] = f2h(ov * rstd * wc + bc);
        }
    } else {
        float acc = 0.f;
        for (int n = s; n < e; n++) acc += h2f(h[(size_t)n * Hh + c]);
        float mean = acc / cntf;
        float sq = 0.f;
        for (int n = s; n < e; n++) {
            float ov = h2f(f2h(h2f(h[(size_t)n * Hh + c]) - msc * mean));
            sq += ov * ov;
        }
        float rstd = rsqrtf(sq / cntf + EPSc);
        for (int n = s; n < e; n++) {
            float ov = h2f(f2h(h2f(h[(size_t)n * Hh + c]) - msc * mean));
            outp[(size_t)n * Hh + c] = f2h(ov * rstd * wc + bc);
        }
    }
}

// =====================================================================================
extern "C" void kernel_launch(void* const* d_in, const int* in_sizes, int n_in,
                              void* d_out, int out_size, void* d_ws, size_t ws_size,
                              hipStream_t stream) {
    const int* x_idx      = (const int*)d_in[0];
    const int* edge_index = (const int*)d_in[2];
    const int* batch      = (const int*)d_in[3];
    const float* feature1 = (const float*)d_in[4];
    const float* feature2 = (const float*)d_in[5];
    const float* x_tab    = (const float*)d_in[6];
    const float* linx_w   = (const float*)d_in[8];
    const float* linx_b   = (const float*)d_in[9];
    const float* linx_g   = (const float*)d_in[10];
    const float* linx_be  = (const float*)d_in[11];
    const float* f1_w1    = (const float*)d_in[12];
    const float* f1_b1    = (const float*)d_in[13];
    const float* f1_g     = (const float*)d_in[14];
    const float* f1_be    = (const float*)d_in[15];
    const float* f1_w2    = (const float*)d_in[16];
    const float* f1_b2    = (const float*)d_in[17];
    const float* f2_w1    = (const float*)d_in[18];
    const float* f2_b1    = (const float*)d_in[19];
    const float* f2_g     = (const float*)d_in[20];
    const float* f2_be    = (const float*)d_in[21];
    const float* f2_w2    = (const float*)d_in[22];
    const float* f2_b2    = (const float*)d_in[23];
    const float* c1_rel_w  = (const float*)d_in[24];
    const float* c1_rel_b  = (const float*)d_in[25];
    const float* c1_root_w = (const float*)d_in[26];
    const float* c2_rel_w  = (const float*)d_in[27];
    const float* c2_rel_b  = (const float*)d_in[28];
    const float* c2_root_w = (const float*)d_in[29];
    const float* cat_w    = (const float*)d_in[30];
    const float* cat_b    = (const float*)d_in[31];
    const float* lins_w   = (const float*)d_in[32];
    const float* lins_b   = (const float*)d_in[33];
    const float* gn_w     = (const float*)d_in[34];
    const float* gn_b     = (const float*)d_in[35];
    const float* gn_ms    = (const float*)d_in[36];
    const float* fin_w    = (const float*)d_in[37];
    const float* fin_b    = (const float*)d_in[38];

    size_t NH = (size_t)Nn * Hh;
    char* p = (char*)d_ws;
    ushortt* X  = (ushortt*)p; p += NH * 2;
    ushortt* B1 = (ushortt*)p; p += NH * 2;
    ushortt* B2 = (ushortt*)p; p += NH * 2;
    ushortt* B3 = (ushortt*)p; p += NH * 2;
    // d_out doubles as agg scratch: fp16 (single chunk) or fp32 (fallback)
    float* aggF = (float*)d_out;
    ushortt* aggH = (ushortt*)d_out;
    float* colsum = (float*)p; p += 256 * 4;
    float* colsq  = (float*)p; p += 256 * 4;
    float* part = (float*)p; p += (size_t)CSB * 512 * 4;
    float* G1 = (float*)p; p += 160 * 4;
    float* s1 = (float*)p; p += 16 * 4;
    float* G2 = (float*)p; p += 48 * 4;
    float* s2 = (float*)p; p += 16 * 4;
    float* scsAll = (float*)p; p += 8 * 64 * 4;
    float* shsAll = (float*)p; p += 8 * 64 * 4;
    int* gstart = (int*)p; p += 2048 * 4;
    int* deg    = (int*)p; p += Nn * 4;
    int* iscan  = (int*)p; p += Nn * 4;
    int* rowptr = (int*)p; p += (Nn + 256) * 4;
    int* cursor = (int*)p; p += Nn * 4;
    int* bsum   = (int*)p; p += 256 * 4;
    int* ebase  = (int*)p; p += 256 * 4;
    int* eid    = (int*)p; p += (size_t)Ee * 4;
    int* esrc   = (int*)p; p += (size_t)Ee * 4;
    // dst-sorted fp16 edge features
    ushortt* featS1 = (ushortt*)p; p += (size_t)Ee * F1c * 2;
    ushortt* featS2 = (ushortt*)p; p += (size_t)Ee * 6 * 2;
    // fp16 weight buffers (fragment-coalesced)
    ushortt* linxW = (ushortt*)p; p += (size_t)4 * 65536 * 2;
    ushortt* convW = (ushortt*)p; p += (size_t)16 * 65536 * 2;
    ushortt* catW  = (ushortt*)p; p += (size_t)8 * 65536 * 2;
    ushortt* linsW = (ushortt*)p; p += (size_t)12 * 65536 * 2;
    ushortt* finW  = (ushortt*)p; p += (size_t)4 * 65536 * 2;
    ushortt* fw2W  = (ushortt*)p; p += (size_t)8 * 16384 * 2;
    // chunk buffer: Wc [CE,256] fp16 (single chunk preferred)
    long availB = (long)ws_size - (long)(p - (char*)d_ws) - 1024;
    int CE = (int)(availB / (Hh * 2));
    if (CE > Ee) CE = Ee;
    if (CE < 8000) CE = 8000;
    ushortt* Wcb = (ushortt*)p;
    int single = (CE >= Ee) ? 1 : 0;

    long tot4 = (long)NH / 4;
    int blks4 = (int)((tot4 + 255) / 256);
    int blksE = (Ee + 255) / 256;
    int blksN = (Nn + 255) / 256;

    embed_x_kernel<<<Nn, 256, 0, stream>>>(x_idx, x_tab, X);
    seg_bounds_kernel<<<(Gc + 256) / 256, 256, 0, stream>>>(batch, gstart);
    hipMemsetAsync(deg, 0, Nn * sizeof(int), stream);
    deg_hist_kernel<<<blksE, 256, 0, stream>>>(edge_index, deg);
    psum_block_kernel<<<NB, 256, 0, stream>>>(deg, iscan, bsum);
    scan_bsum_kernel<<<1, 64, 0, stream>>>(bsum, ebase, rowptr);
    finalize_rowptr_kernel<<<blksN, 256, 0, stream>>>(deg, iscan, ebase, rowptr);
    hipMemcpyAsync(cursor, rowptr, Nn * sizeof(int), hipMemcpyDeviceToDevice, stream);
    fill_eid_kernel<<<blksE, 256, 0, stream>>>(edge_index, cursor, eid, esrc);
    gather_feat_kernel<F1c><<<(int)(((long)Ee * F1c + 255) / 256), 256, 0, stream>>>(
        feature1, eid, featS1);
    gather_feat_kernel<6><<<(int)(((long)Ee * 6 + 255) / 256), 256, 0, stream>>>(
        feature2, eid, featS2);

    hipMemsetAsync(G1, 0, 240 * sizeof(float), stream);
    gram_kernel<F1c><<<240, 256, 0, stream>>>(feature1, G1, s1);
    gram_kernel<6><<<240, 256, 0, stream>>>(feature2, G2, s2);
    edge_bnparams_kernel<<<8, 64, 0, stream>>>(G1, s1, G2, s2,
                                               f1_w1, f1_b1, f1_g, f1_be,
                                               f2_w1, f2_b1, f2_g, f2_be,
                                               (float)Ee, scsAll, shsAll);

    auto wcv = [&](const float* src, ushortt* dh, int nmat, int K,
                   long dstMS, int kOff, long srcMS) {
        long tot = (long)nmat * 256 * K;
        wconv_kernel<<<(int)((tot + 255) / 256), 256, 0, stream>>>(src, dh, nmat, K,
                                                                   dstMS, kOff, srcMS);
    };
    wcv(linx_w, linxW, 4, 256, 65536, 0, 65536);
    wcv(c1_rel_w,  convW,          4, 256, 262144, 0,   65536);
    wcv(c1_root_w, convW,          4, 256, 262144, 256, 65536);
    wcv(c2_rel_w,  convW + 131072, 4, 256, 262144, 0,   65536);
    wcv(c2_root_w, convW + 131072, 4, 256, 262144, 256, 65536);
    wcv(cat_w, catW, 4, 512, 131072, 0, 131072);
    wcv(lins_w, linsW, 12, 256, 65536, 0, 65536);
    wcv(fin_w, finW, 4, 256, 65536, 0, 65536);
    wcv(f1_w2, fw2W,         4, 64, 32768, 0, 16384);
    wcv(f2_w2, fw2W + 16384, 4, 64, 32768, 0, 16384);

    dim3 gN(2, (Nn + 127) / 128);   // x = col-half (fastest) -> A-row L2 reuse

    for (int l = 0; l < Lc; l++) {
        // T = x @ linx_w + b -> B1 (fp16); xl = relu(BN(T)) -> X
        bgemm_kernel<<<gN, 256, 0, stream>>>(X, 256, nullptr, 0,
                                             linxW + (size_t)l * 65536,
                                             linx_b + l * Hh, nullptr, nullptr, B1,
                                             Nn, 256, 256, 0, 0);
        colstats_part_kernel<<<CSB, 256, 0, stream>>>(B1, tot4, part);
        colstats_reduce_kernel<<<2, 256, 0, stream>>>(part, colsum, colsq);
        bn_relu_h_kernel<<<blks4, 256, 0, stream>>>(B1, X, colsum, colsq,
                                                    linx_g + l * Hh, linx_be + l * Hh,
                                                    1.f / Nn, tot4);

        for (int br = 0; br < 2; br++) {
            const float* fw1 = br == 0 ? f1_w1 + (size_t)l * F1c * Mm : f2_w1 + (size_t)l * 6 * Mm;
            const float* fb2 = br == 0 ? f1_b2 + l * Hh : f2_b2 + l * Hh;
            const float* relb = br == 0 ? c1_rel_b + l * Hh : c2_rel_b + l * Hh;
            ushortt* fw2t = fw2W + (size_t)l * 32768 + (br ? 16384 : 0);
            ushortt* cvt  = convW + (size_t)l * 262144 + (br ? 131072 : 0);
            ushortt* hbr = br == 0 ? B3 : B2;
            const float* scsP = scsAll + (l * 2 + br) * 64;
            const float* shsP = shsAll + (l * 2 + br) * 64;

            for (int c0 = 0; c0 < Ee; c0 += CE) {
                int ec = Ee - c0 < CE ? Ee - c0 : CE;
                dim3 gc(2, (ec + 127) / 128);
                if (br == 0)
                    edge_gemm_kernel<F1c><<<gc, 256, 0, stream>>>(
                        featS1, fw1, scsP, shsP, fw2t, fb2, Wcb, c0, ec);
                else
                    edge_gemm_kernel<6><<<gc, 256, 0, stream>>>(
                        featS2, fw1, scsP, shsP, fw2t, fb2, Wcb, c0, ec);
                gather_agg_kernel<<<(Nn * 64 + 255) / 256, 256, 0, stream>>>(
                    rowptr, esrc, Wcb, X, aggF, single ? aggH : nullptr,
                    c0, c0 + ec, c0 == 0 ? 1 : 0);
            }
            // h_br = relu(agg @ rel_w + xl @ root_w + rel_b)
            if (single)
                bgemm_kernel<<<gN, 256, 0, stream>>>(aggH, 256, X, 256, cvt,
                                                     relb, nullptr, nullptr, hbr,
                                                     Nn, 256, 512, 1, 0);
            else
                bgemm_kernel<<<gN, 256, 0, stream>>>(aggF, 256, X, 256, cvt,
                                                     relb, nullptr, nullptr, hbr,
                                                     Nn, 256, 512, 1, 1);
        }

        // h = relu([h1,h2] @ cat_w + cat_b) + xl -> B1
        bgemm_kernel<<<gN, 256, 0, stream>>>(B3, 256, B2, 256,
                                             catW + (size_t)l * 131072,
                                             cat_b + l * Hh, X, nullptr, B1,
                                             Nn, 256, 512, 1, 0);
        // residual linears: B1 <-> B2
        ushortt* cur = B1; ushortt* oth = B2;
        for (int k = 0; k < NLc; k++) {
            bgemm_kernel<<<gN, 256, 0, stream>>>(cur, 256, nullptr, 0,
                                                 linsW + ((size_t)l * NLc + k) * 65536,
                                                 lins_b + ((size_t)l * NLc + k) * Hh, cur,
                                                 nullptr, oth, Nn, 256, 256, 1, 0);
            ushortt* t = cur; cur = oth; oth = t;
        }
        // cur == B2. Fused GraphNorm: cur -> oth (one read + one write)
        gn_fused_kernel<<<Gc, 256, 0, stream>>>(cur, gstart, gn_ms + l * Hh,
                                                gn_w + l * Hh, gn_b + l * Hh, oth);
        // x_next = h @ fin_w + fin_b
        bgemm_kernel<<<gN, 256, 0, stream>>>(oth, 256, nullptr, 0,
                                             finW + (size_t)l * 65536,
                                             fin_b + l * Hh, nullptr,
                                             (l == Lc - 1) ? (float*)d_out : nullptr,
                                             (l == Lc - 1) ? nullptr : X,
                                             Nn, 256, 256, 0, 0);
    }
}

// Round 19
// 2633.267 us; speedup vs baseline: 1.4645x; 1.0206x over previous
//
#include <hip/hip_runtime.h>
#include <cstdint>

constexpr int Nn = 60000;
constexpr int Ee = 240000;
constexpr int Hh = 256;
constexpr int Mm = 64;
constexpr int F1c = 12;
constexpr int Lc = 4;
constexpr int NLc = 3;
constexpr int Gc = 2000;
constexpr float EPSc = 1e-5f;
constexpr int NB = (Nn + 255) / 256;
constexpr int CSB = 256;   // colstats blocks

typedef _Float16 f16x8 __attribute__((ext_vector_type(8)));
typedef __attribute__((ext_vector_type(4))) float f32x4;
typedef __attribute__((ext_vector_type(4))) unsigned short u16x4;
typedef unsigned short ushortt;

__device__ __forceinline__ ushortt f2h(float f) {
    union { _Float16 h; ushortt u; } c; c.h = (_Float16)f; return c.u;
}
__device__ __forceinline__ float h2f(ushortt u) {
    union { _Float16 h; ushortt u; } c; c.u = u; return (float)c.h;
}

// ---------------- embedding -> fp16 ----------------
__global__ void embed_x_kernel(const int* __restrict__ xidx, const float* __restrict__ xtab,
                               ushortt* __restrict__ x) {
    int n = blockIdx.x;
    int c = threadIdx.x;
    __shared__ int idx[9];
    if (c < 9) idx[c] = xidx[n * 9 + c];
    __syncthreads();
    float s = 0.f;
#pragma unroll
    for (int j = 0; j < 9; j++) s += xtab[idx[j] * Hh + c];
    x[(size_t)n * Hh + c] = f2h(s);
}

__global__ void seg_bounds_kernel(const int* __restrict__ batch, int* __restrict__ gstart) {
    int g = blockIdx.x * 256 + threadIdx.x;
    if (g > Gc) return;
    if (g == Gc) { gstart[Gc] = Nn; return; }
    int lo = 0, hi = Nn;
    while (lo < hi) { int mid = (lo + hi) >> 1; if (batch[mid] < g) lo = mid + 1; else hi = mid; }
    gstart[g] = lo;
}

// ---------------- CSR build ----------------
__global__ void deg_hist_kernel(const int* __restrict__ ei, int* __restrict__ deg) {
    int e = blockIdx.x * 256 + threadIdx.x;
    if (e >= Ee) return;
    atomicAdd(&deg[ei[Ee + e]], 1);
}

__global__ void psum_block_kernel(const int* __restrict__ deg, int* __restrict__ iscan,
                                  int* __restrict__ bsum) {
    __shared__ int s[256];
    int t = threadIdx.x;
    int i = blockIdx.x * 256 + t;
    int v = (i < Nn) ? deg[i] : 0;
    s[t] = v;
    __syncthreads();
    for (int off = 1; off < 256; off <<= 1) {
        int add = (t >= off) ? s[t - off] : 0;
        __syncthreads();
        s[t] += add;
        __syncthreads();
    }
    if (i < Nn) iscan[i] = s[t];
    if (t == 255) bsum[blockIdx.x] = s[255];
}

__global__ void scan_bsum_kernel(const int* __restrict__ bsum, int* __restrict__ ebase,
                                 int* __restrict__ rowptr) {
    if (threadIdx.x != 0 || blockIdx.x != 0) return;
    int run = 0;
    for (int b = 0; b < NB; b++) { ebase[b] = run; run += bsum[b]; }
    rowptr[Nn] = Ee;
}

__global__ void finalize_rowptr_kernel(const int* __restrict__ deg, const int* __restrict__ iscan,
                                       const int* __restrict__ ebase, int* __restrict__ rowptr) {
    int i = blockIdx.x * 256 + threadIdx.x;
    if (i >= Nn) return;
    rowptr[i] = ebase[i >> 8] + iscan[i] - deg[i];
}

__global__ void fill_eid_kernel(const int* __restrict__ ei, int* __restrict__ cursor,
                                int* __restrict__ eid, int* __restrict__ esrc) {
    int e = blockIdx.x * 256 + threadIdx.x;
    if (e >= Ee) return;
    int dst = ei[Ee + e];
    int pos = atomicAdd(&cursor[dst], 1);
    eid[pos] = e;
    esrc[pos] = ei[e];
}

// ------- gather features into dst-sorted order, fp16 (once) -----------------------
template<int K>
__global__ void gather_feat_kernel(const float* __restrict__ F, const int* __restrict__ eid,
                                   ushortt* __restrict__ featS) {
    long i = (long)blockIdx.x * 256 + threadIdx.x;
    if (i >= (long)Ee * K) return;
    int e = (int)(i / K);
    int k = (int)(i % K);
    featS[i] = f2h(F[(size_t)eid[e] * K + k]);
}

// ------- weight f32->f16, fragment-coalesced layout [ks][col 256][32 packed] -------
__global__ void wconv_kernel(const float* __restrict__ src, ushortt* __restrict__ dst,
                             int nmat, int K, long dstMS, int kOff, long srcMS) {
    long idx = (long)blockIdx.x * 256 + threadIdx.x;
    long tot = (long)nmat * 256 * K;
    if (idx >= tot) return;
    int k = (int)(idx % K);
    long t = idx / K;
    int c = (int)(t & 255);
    int m = (int)(t >> 8);
    float w = src[m * srcMS + (long)k * 256 + c];
    int kg = kOff + k;
    int ks = kg >> 5;
    int k5 = kg & 31;
    int kpp = (((k5 & 15) >> 2) << 3) + (((k5 >> 4) & 1) << 2) + (k5 & 3);
    long o = m * dstMS + ((long)ks * 256 + c) * 32 + kpp;
    dst[o] = f2h(w);
}

// ---------------- Gram via LDS tiles ------------------------------------------------
template<int K>
__global__ void gram_kernel(const float* __restrict__ F, float* __restrict__ G,
                            float* __restrict__ s) {
    constexpr int NP = K * (K + 1) / 2;
    __shared__ float Ft[256 * K];
    int tid = threadIdx.x;
    int pi = 0, pj = 0;
    if (tid < NP) {
        int tt = tid;
        for (pi = 0; pi < K; pi++) { if (tt <= pi) { pj = tt; break; } tt -= (pi + 1); }
    }
    float acc = 0.f;
    int ntiles = (Ee + 255) / 256;
    for (int tile = blockIdx.x; tile < ntiles; tile += gridDim.x) {
        long r0 = (long)tile * 256;
        for (int idx = tid; idx < 256 * K; idx += 256) {
            long r = r0 + idx / K;
            Ft[idx] = (r < Ee) ? F[r * K + idx % K] : 0.f;
        }
        __syncthreads();
        if (tid < NP) {
            for (int r = 0; r < 256; r++) acc += Ft[r * K + pi] * Ft[r * K + pj];
        } else if (tid < NP + K) {
            int i = tid - NP;
            for (int r = 0; r < 256; r++) acc += Ft[r * K + i];
        }
        __syncthreads();
    }
    if (tid < NP) {
        atomicAdd(&G[pi * K + pj], acc);
        if (pi != pj) atomicAdd(&G[pj * K + pi], acc);
    } else if (tid < NP + K) {
        atomicAdd(&s[tid - NP], acc);
    }
}

// ------- setup: folded edge-BN affine per (layer, branch) --------------------------
__global__ void edge_bnparams_kernel(
    const float* __restrict__ G1, const float* __restrict__ s1,
    const float* __restrict__ G2, const float* __restrict__ s2,
    const float* __restrict__ f1_w1, const float* __restrict__ f1_b1,
    const float* __restrict__ f1_g, const float* __restrict__ f1_be,
    const float* __restrict__ f2_w1, const float* __restrict__ f2_b1,
    const float* __restrict__ f2_g, const float* __restrict__ f2_be,
    float Ecnt, float* __restrict__ scsAll, float* __restrict__ shsAll) {
    int lb = blockIdx.x;          // l*2 + br, 8 blocks
    int l = lb >> 1, br = lb & 1;
    int m = threadIdx.x;          // 64
    const float* G = br ? G2 : G1;
    const float* sv = br ? s2 : s1;
    int K = br ? 6 : F1c;
    const float* W  = br ? (f2_w1 + (size_t)l * 6 * Mm)   : (f1_w1 + (size_t)l * F1c * Mm);
    const float* bb = br ? (f2_b1 + l * Mm) : (f1_b1 + l * Mm);
    const float* gg = br ? (f2_g + l * Mm)  : (f1_g + l * Mm);
    const float* be = br ? (f2_be + l * Mm) : (f1_be + l * Mm);
    float wm[F1c];
    for (int i = 0; i < K; i++) wm[i] = W[i * Mm + m];
    float sw = 0.f;
    for (int i = 0; i < K; i++) sw += sv[i] * wm[i];
    float q = 0.f;
    for (int i = 0; i < K; i++) {
        float gi = 0.f;
        for (int j = 0; j < K; j++) gi += G[i * K + j] * wm[j];
        q += wm[i] * gi;
    }
    float rinv = 1.f / Ecnt;
    float colsum = sw + Ecnt * bb[m];
    float colsq = q + 2.f * bb[m] * sw + Ecnt * bb[m] * bb[m];
    float mu = colsum * rinv;
    float var = colsq * rinv - mu * mu;
    float rs = rsqrtf(var + EPSc) * gg[m];
    scsAll[lb * 64 + m] = rs;
    shsAll[lb * 64 + m] = bb[m] * rs + be[m] - mu * rs;
}

// ---------------- node BN stats: per-block partials (no atomics) -------------------
__global__ void colstats_part_kernel(const ushortt* __restrict__ A, long tot4,
                                     float* __restrict__ part) {
    __shared__ float ls[1024], lq[1024];
    int tid = threadIdx.x;
    long i0 = (long)blockIdx.x * 256 + tid;
    long stride = (long)gridDim.x * 256;
    float s[4] = {0, 0, 0, 0}, q[4] = {0, 0, 0, 0};
    for (long i = i0; i < tot4; i += stride) {
        u16x4 v = *(const u16x4*)(A + i * 4);
#pragma unroll
        for (int j = 0; j < 4; j++) { float f = h2f(v[j]); s[j] += f; q[j] += f * f; }
    }
#pragma unroll
    for (int j = 0; j < 4; j++) { ls[tid * 4 + j] = s[j]; lq[tid * 4 + j] = q[j]; }
    __syncthreads();
    if (tid < 64) {
#pragma unroll
        for (int j = 0; j < 4; j++) {
            float ts = ls[tid * 4 + j] + ls[(tid + 64) * 4 + j] +
                       ls[(tid + 128) * 4 + j] + ls[(tid + 192) * 4 + j];
            float tq = lq[tid * 4 + j] + lq[(tid + 64) * 4 + j] +
                       lq[(tid + 128) * 4 + j] + lq[(tid + 192) * 4 + j];
            part[(size_t)blockIdx.x * 512 + tid * 4 + j] = ts;
            part[(size_t)blockIdx.x * 512 + 256 + tid * 4 + j] = tq;
        }
    }
}

__global__ void colstats_reduce_kernel(const float* __restrict__ part,
                                       float* __restrict__ colsum, float* __restrict__ colsq) {
    int t = blockIdx.x * 256 + threadIdx.x;   // 0..511
    float acc = 0.f;
    for (int b = 0; b < CSB; b++) acc += part[(size_t)b * 512 + t];
    if (t < 256) colsum[t] = acc;
    else colsq[t - 256] = acc;
}

__global__ void bn_relu_h_kernel(const ushortt* __restrict__ A, ushortt* __restrict__ outp,
                                 const float* __restrict__ sum, const float* __restrict__ sq,
                                 const float* __restrict__ g, const float* __restrict__ be,
                                 float rinv, long tot4) {
    long i = (long)blockIdx.x * 256 + threadIdx.x;
    if (i >= tot4) return;
    int c0 = (int)((i * 4) & 255);
    u16x4 v = *(const u16x4*)(A + i * 4);
    u16x4 o;
#pragma unroll
    for (int j = 0; j < 4; j++) {
        int c = c0 + j;
        float m = sum[c] * rinv;
        float var = sq[c] * rinv - m * m;
        float f = (h2f(v[j]) - m) * rsqrtf(var + EPSc) * g[c] + be[c];
        o[j] = f2h(fmaxf(f, 0.f));
    }
    *(u16x4*)(outp + i * 4) = o;
}

// ---------------- fp16 MFMA GEMM v9: BK=64 per barrier round -----------------------
__global__ __launch_bounds__(256, 4) void bgemm_kernel(
    const void* __restrict__ A1v, int lda1, const ushortt* __restrict__ A2, int lda2,
    const ushortt* __restrict__ Wt,
    const float* __restrict__ bias, const ushortt* __restrict__ res,
    float* __restrict__ Cf, ushortt* __restrict__ Ch,
    int rows, int K1, int Ktot, int do_relu, int a1f32) {
    __shared__ char As[2][128 * 80];
    int tid = threadIdx.x;
    int lane = tid & 63;
    int wave = tid >> 6;
    int wrow0 = (wave >> 1) * 64;
    int wcol0 = (wave & 1) * 64;
    int r0 = blockIdx.y * 128;
    int j0 = blockIdx.x * 128;
    int l15 = lane & 15;
    int l4 = lane >> 4;

    int srow[4], sk4[4], soff[4];
#pragma unroll
    for (int p = 0; p < 4; p++) {
        int fid = p * 256 + tid;
        srow[p] = fid >> 3;
        sk4[p] = (fid & 7) * 4;
        soff[p] = srow[p] * 80 + ((((sk4[p] & 15) >> 2) << 4) + ((sk4[p] >> 4) << 3));
    }

    f32x4 acc[4][4];
#pragma unroll
    for (int i = 0; i < 4; i++)
#pragma unroll
        for (int j = 0; j < 4; j++) acc[i][j] = (f32x4){0.f, 0.f, 0.f, 0.f};

    for (int kt = 0; kt < Ktot; kt += 64) {
        const void* Av; int lda; int koff; int f32;
        if (kt < K1) { Av = A1v; lda = lda1; koff = kt; f32 = a1f32; }
        else         { Av = (const void*)A2; lda = lda2; koff = kt - K1; f32 = 0; }

        u16x4 hv[2][4];
        if (f32) {
#pragma unroll
            for (int h = 0; h < 2; h++)
#pragma unroll
                for (int p = 0; p < 4; p++) {
                    int rg = r0 + srow[p]; if (rg >= rows) rg = rows - 1;
                    float4 v = *(const float4*)((const float*)Av +
                        (size_t)rg * lda + koff + h * 32 + sk4[p]);
                    u16x4 hh;
                    hh[0] = f2h(v.x); hh[1] = f2h(v.y); hh[2] = f2h(v.z); hh[3] = f2h(v.w);
                    hv[h][p] = hh;
                }
        } else {
#pragma unroll
            for (int h = 0; h < 2; h++)
#pragma unroll
                for (int p = 0; p < 4; p++) {
                    int rg = r0 + srow[p]; if (rg >= rows) rg = rows - 1;
                    hv[h][p] = *(const u16x4*)((const ushortt*)Av +
                        (size_t)rg * lda + koff + h * 32 + sk4[p]);
                }
        }
        f16x8 bh[2][4];
#pragma unroll
        for (int h = 0; h < 2; h++) {
            long kb = ((long)((kt + h * 32) >> 5) * 256) * 32;
#pragma unroll
            for (int j = 0; j < 4; j++) {
                int colrow = j0 + wcol0 + j * 16 + l15;
                bh[h][j] = *(const f16x8*)(Wt + kb + (long)colrow * 32 + l4 * 8);
            }
        }
#pragma unroll
        for (int h = 0; h < 2; h++)
#pragma unroll
            for (int p = 0; p < 4; p++) *(u16x4*)(As[h] + soff[p]) = hv[h][p];
        __syncthreads();

#pragma unroll
        for (int h = 0; h < 2; h++) {
            f16x8 ah[4];
#pragma unroll
            for (int i = 0; i < 4; i++) {
                int row = wrow0 + i * 16 + l15;
                ah[i] = *(const f16x8*)(As[h] + row * 80 + l4 * 16);
            }
#pragma unroll
            for (int i = 0; i < 4; i++)
#pragma unroll
                for (int j = 0; j < 4; j++)
                    acc[i][j] = __builtin_amdgcn_mfma_f32_16x16x32_f16(ah[i], bh[h][j], acc[i][j], 0, 0, 0);
        }
        __syncthreads();
    }

#pragma unroll
    for (int i = 0; i < 4; i++) {
#pragma unroll
        for (int r = 0; r < 4; r++) {
            int row = r0 + wrow0 + i * 16 + l4 * 4 + r;
            if (row >= rows) continue;
#pragma unroll
            for (int j = 0; j < 4; j++) {
                int col = j0 + wcol0 + j * 16 + l15;
                float v = acc[i][j][r] + bias[col];
                if (do_relu) v = fmaxf(v, 0.f);
                if (res) v += h2f(res[(size_t)row * 256 + col]);
                if (Cf) Cf[(size_t)row * 256 + col] = v;
                if (Ch) Ch[(size_t)row * 256 + col] = f2h(v);
            }
        }
    }
}

// ---------------- fused edge kernel: U = relu((featS@W1)*scs+shs); Wc = relu(U@W2+b2)
// Epilogue: LDS-staged coalesced stores (reuses As after MFMA loop).
template<int K>
__global__ __launch_bounds__(256, 4) void edge_gemm_kernel(
    const ushortt* __restrict__ featS, const float* __restrict__ W1,
    const float* __restrict__ scs, const float* __restrict__ shs,
    const ushortt* __restrict__ Wt, const float* __restrict__ bias,
    ushortt* __restrict__ Wc, int c0, int ec) {
    constexpr int KP = K + 1;          // pad: stride coprime with 32 banks
    __shared__ char As[2][128 * 80];
    __shared__ float Fs[128 * KP];
    __shared__ float W1s[K * 64];
    __shared__ float scsS[64], shsS[64];
    int tid = threadIdx.x;
    for (int i = tid; i < K * 64; i += 256) W1s[i] = W1[i];
    if (tid < 64) { scsS[tid] = scs[tid]; shsS[tid] = shs[tid]; }
    int r0 = blockIdx.y * 128;
    for (int idx = tid; idx < 128 * K; idx += 256) {
        int row = idx / K;
        int k = idx % K;
        long e = (long)c0 + r0 + row;
        if (e >= Ee) e = Ee - 1;
        Fs[row * KP + k] = h2f(featS[e * K + k]);
    }
    __syncthreads();
    {
        int row = tid >> 1;
        int m0 = (tid & 1) * 32;
        const float* fr = &Fs[row * KP];
#pragma unroll
        for (int mm = 0; mm < 32; mm++) {
            int m = m0 + mm;
            float u = 0.f;
#pragma unroll
            for (int k = 0; k < K; k++) u += fr[k] * W1s[k * 64 + m];
            float v = fmaxf(u * scsS[m] + shsS[m], 0.f);
            int k5 = m & 31;
            int kpp = (((k5 & 15) >> 2) << 3) + (((k5 >> 4) & 1) << 2) + (k5 & 3);
            *(ushortt*)(As[m >> 5] + row * 80 + kpp * 2) = f2h(v);
        }
    }
    __syncthreads();

    int lane = tid & 63;
    int wave = tid >> 6;
    int wrow0 = (wave >> 1) * 64;
    int wcol0 = (wave & 1) * 64;
    int j0 = blockIdx.x * 128;
    int l15 = lane & 15;
    int l4 = lane >> 4;

    f32x4 acc[4][4];
#pragma unroll
    for (int i = 0; i < 4; i++)
#pragma unroll
        for (int j = 0; j < 4; j++) acc[i][j] = (f32x4){0.f, 0.f, 0.f, 0.f};

#pragma unroll
    for (int kt = 0; kt < 64; kt += 32) {
        f16x8 bh[4];
        long kb = ((long)(kt >> 5) * 256) * 32;
#pragma unroll
        for (int j = 0; j < 4; j++) {
            int colrow = j0 + wcol0 + j * 16 + l15;
            bh[j] = *(const f16x8*)(Wt + kb + (long)colrow * 32 + l4 * 8);
        }
        f16x8 ah[4];
        const char* Az = As[kt >> 5];
#pragma unroll
        for (int i = 0; i < 4; i++) {
            int row = wrow0 + i * 16 + l15;
            ah[i] = *(const f16x8*)(Az + row * 80 + l4 * 16);
        }
#pragma unroll
        for (int i = 0; i < 4; i++)
#pragma unroll
            for (int j = 0; j < 4; j++)
                acc[i][j] = __builtin_amdgcn_mfma_f32_16x16x32_f16(ah[i], bh[j], acc[i][j], 0, 0, 0);
    }

    // ---- LDS-staged coalesced epilogue (reuses As: 64x128 fp16 = 16 KB) ----
    __syncthreads();
    ushortt* stg = (ushortt*)As[0];
#pragma unroll
    for (int half = 0; half < 2; half++) {
        if ((wave >> 1) == half) {
#pragma unroll
            for (int i = 0; i < 4; i++)
#pragma unroll
                for (int r = 0; r < 4; r++) {
                    int lrow = i * 16 + l4 * 4 + r;
#pragma unroll
                    for (int j = 0; j < 4; j++) {
                        int col = wcol0 + j * 16 + l15;
                        float v = fmaxf(acc[i][j][r] + bias[j0 + col], 0.f);
                        stg[lrow * 128 + col] = f2h(v);
                    }
                }
        }
        __syncthreads();
#pragma unroll
        for (int it = 0; it < 4; it++) {
            int lrow = it * 16 + (tid >> 4);
            int row = r0 + half * 64 + lrow;
            if (row < ec) {
                int ce = (tid & 15) * 8;
                *(uint4*)(Wc + (size_t)row * 256 + j0 + ce) =
                    *(const uint4*)(stg + lrow * 128 + ce);
            }
        }
        __syncthreads();
    }
}

// ------- gather-aggregate (fp16 Wc, fp16 xl; fp32 reg acc) -------------------------
__global__ __launch_bounds__(256) void gather_agg_kernel(
    const int* __restrict__ rowptr, const int* __restrict__ esrc,
    const ushortt* __restrict__ Wc, const ushortt* __restrict__ xl,
    float* __restrict__ agg, ushortt* __restrict__ out16, int c0, int c1, int first) {
    int n = (blockIdx.x * 256 + threadIdx.x) >> 6;
    if (n >= Nn) return;
    int lane = threadIdx.x & 63;
    int rs = rowptr[n], re = rowptr[n + 1];
    if (rs < c0) rs = c0;
    if (re > c1) re = c1;
    float4 acc;
    if (out16 || first) {
        acc = make_float4(0.f, 0.f, 0.f, 0.f);
    } else {
        if (rs >= re) return;
        acc = *(float4*)(agg + (size_t)n * Hh + lane * 4);
    }
    for (int i = rs; i < re; i++) {
        u16x4 wv = *(const u16x4*)(Wc + (size_t)(i - c0) * Hh + lane * 4);
        u16x4 xv = *(const u16x4*)(xl + (size_t)esrc[i] * Hh + lane * 4);
        acc.x += h2f(wv[0]) * h2f(xv[0]);
        acc.y += h2f(wv[1]) * h2f(xv[1]);
        acc.z += h2f(wv[2]) * h2f(xv[2]);
        acc.w += h2f(wv[3]) * h2f(xv[3]);
    }
    if (out16) {
        u16x4 o;
        o[0] = f2h(acc.x); o[1] = f2h(acc.y); o[2] = f2h(acc.z); o[3] = f2h(acc.w);
        *(u16x4*)(out16 + (size_t)n * Hh + lane * 4) = o;
    } else {
        *(float4*)(agg + (size_t)n * Hh + lane * 4) = acc;
    }
}

// ---------------- fused GraphNorm: one block per graph, segment in LDS -------------
__global__ __launch_bounds__(256) void gn_fused_kernel(
    const ushortt* __restrict__ h, const int* __restrict__ gstart,
    const float* __restrict__ ms, const float* __restrict__ w, const float* __restrict__ b,
    ushortt* __restrict__ outp) {
    __shared__ ushortt seg[128 * 256];
    int g = blockIdx.x;
    int c = threadIdx.x;
    int s = gstart[g], e = gstart[g + 1];
    int cnt = e - s;
    float cntf = (float)(cnt > 1 ? cnt : 1);
    float msc = ms[c], wc = w[c], bc = b[c];
    if (cnt <= 128) {
        float acc = 0.f;
        for (int n = 0; n < cnt; n++) {
            ushortt v = h[(size_t)(s + n) * Hh + c];
            seg[n * 256 + c] = v;
            acc += h2f(v);
        }
        float mean = acc / cntf;
        float sq = 0.f;
        for (int n = 0; n < cnt; n++) {
            ushortt ho = f2h(h2f(seg[n * 256 + c]) - msc * mean);
            seg[n * 256 + c] = ho;
            float o2 = h2f(ho);
            sq += o2 * o2;
        }
        float rstd = rsqrtf(sq / cntf + EPSc);
        for (int n = 0; n < cnt; n++) {
            float ov = h2f(seg[n * 256 + c]);
            outp[(size_t)(s + n) * Hh + c] = f2h(ov * rstd * wc + bc);
        }
    } else {
        float acc = 0.f;
        for (int n = s; n < e; n++) acc += h2f(h[(size_t)n * Hh + c]);
        float mean = acc / cntf;
        float sq = 0.f;
        for (int n = s; n < e; n++) {
            float ov = h2f(f2h(h2f(h[(size_t)n * Hh + c]) - msc * mean));
            sq += ov * ov;
        }
        float rstd = rsqrtf(sq / cntf + EPSc);
        for (int n = s; n < e; n++) {
            float ov = h2f(f2h(h2f(h[(size_t)n * Hh + c]) - msc * mean));
            outp[(size_t)n * Hh + c] = f2h(ov * rstd * wc + bc);
        }
    }
}

// =====================================================================================
extern "C" void kernel_launch(void* const* d_in, const int* in_sizes, int n_in,
                              void* d_out, int out_size, void* d_ws, size_t ws_size,
                              hipStream_t stream) {
    const int* x_idx      = (const int*)d_in[0];
    const int* edge_index = (const int*)d_in[2];
    const int* batch      = (const int*)d_in[3];
    const float* feature1 = (const float*)d_in[4];
    const float* feature2 = (const float*)d_in[5];
    const float* x_tab    = (const float*)d_in[6];
    const float* linx_w   = (const float*)d_in[8];
    const float* linx_b   = (const float*)d_in[9];
    const float* linx_g   = (const float*)d_in[10];
    const float* linx_be  = (const float*)d_in[11];
    const float* f1_w1    = (const float*)d_in[12];
    const float* f1_b1    = (const float*)d_in[13];
    const float* f1_g     = (const float*)d_in[14];
    const float* f1_be    = (const float*)d_in[15];
    const float* f1_w2    = (const float*)d_in[16];
    const float* f1_b2    = (const float*)d_in[17];
    const float* f2_w1    = (const float*)d_in[18];
    const float* f2_b1    = (const float*)d_in[19];
    const float* f2_g     = (const float*)d_in[20];
    const float* f2_be    = (const float*)d_in[21];
    const float* f2_w2    = (const float*)d_in[22];
    const float* f2_b2    = (const float*)d_in[23];
    const float* c1_rel_w  = (const float*)d_in[24];
    const float* c1_rel_b  = (const float*)d_in[25];
    const float* c1_root_w = (const float*)d_in[26];
    const float* c2_rel_w  = (const float*)d_in[27];
    const float* c2_rel_b  = (const float*)d_in[28];
    const float* c2_root_w = (const float*)d_in[29];
    const float* cat_w    = (const float*)d_in[30];
    const float* cat_b    = (const float*)d_in[31];
    const float* lins_w   = (const float*)d_in[32];
    const float* lins_b   = (const float*)d_in[33];
    const float* gn_w     = (const float*)d_in[34];
    const float* gn_b     = (const float*)d_in[35];
    const float* gn_ms    = (const float*)d_in[36];
    const float* fin_w    = (const float*)d_in[37];
    const float* fin_b    = (const float*)d_in[38];

    size_t NH = (size_t)Nn * Hh;
    char* p = (char*)d_ws;
    ushortt* X  = (ushortt*)p; p += NH * 2;
    ushortt* B1 = (ushortt*)p; p += NH * 2;
    ushortt* B2 = (ushortt*)p; p += NH * 2;
    ushortt* B3 = (ushortt*)p; p += NH * 2;
    // d_out doubles as agg scratch: fp16 (single chunk) or fp32 (fallback)
    float* aggF = (float*)d_out;
    ushortt* aggH = (ushortt*)d_out;
    float* colsum = (float*)p; p += 256 * 4;
    float* colsq  = (float*)p; p += 256 * 4;
    float* part = (float*)p; p += (size_t)CSB * 512 * 4;
    float* G1 = (float*)p; p += 160 * 4;
    float* s1 = (float*)p; p += 16 * 4;
    float* G2 = (float*)p; p += 48 * 4;
    float* s2 = (float*)p; p += 16 * 4;
    float* scsAll = (float*)p; p += 8 * 64 * 4;
    float* shsAll = (float*)p; p += 8 * 64 * 4;
    int* gstart = (int*)p; p += 2048 * 4;
    int* deg    = (int*)p; p += Nn * 4;
    int* iscan  = (int*)p; p += Nn * 4;
    int* rowptr = (int*)p; p += (Nn + 256) * 4;
    int* cursor = (int*)p; p += Nn * 4;
    int* bsum   = (int*)p; p += 256 * 4;
    int* ebase  = (int*)p; p += 256 * 4;
    int* eid    = (int*)p; p += (size_t)Ee * 4;
    int* esrc   = (int*)p; p += (size_t)Ee * 4;
    // dst-sorted fp16 edge features
    ushortt* featS1 = (ushortt*)p; p += (size_t)Ee * F1c * 2;
    ushortt* featS2 = (ushortt*)p; p += (size_t)Ee * 6 * 2;
    // fp16 weight buffers (fragment-coalesced)
    ushortt* linxW = (ushortt*)p; p += (size_t)4 * 65536 * 2;
    ushortt* convW = (ushortt*)p; p += (size_t)16 * 65536 * 2;
    ushortt* catW  = (ushortt*)p; p += (size_t)8 * 65536 * 2;
    ushortt* linsW = (ushortt*)p; p += (size_t)12 * 65536 * 2;
    ushortt* finW  = (ushortt*)p; p += (size_t)4 * 65536 * 2;
    ushortt* fw2W  = (ushortt*)p; p += (size_t)8 * 16384 * 2;
    // chunk buffer: Wc [CE,256] fp16 (single chunk preferred)
    long availB = (long)ws_size - (long)(p - (char*)d_ws) - 1024;
    int CE = (int)(availB / (Hh * 2));
    if (CE > Ee) CE = Ee;
    if (CE < 8000) CE = 8000;
    ushortt* Wcb = (ushortt*)p;
    int single = (CE >= Ee) ? 1 : 0;

    long tot4 = (long)NH / 4;
    int blks4 = (int)((tot4 + 255) / 256);
    int blksE = (Ee + 255) / 256;
    int blksN = (Nn + 255) / 256;

    embed_x_kernel<<<Nn, 256, 0, stream>>>(x_idx, x_tab, X);
    seg_bounds_kernel<<<(Gc + 256) / 256, 256, 0, stream>>>(batch, gstart);
    hipMemsetAsync(deg, 0, Nn * sizeof(int), stream);
    deg_hist_kernel<<<blksE, 256, 0, stream>>>(edge_index, deg);
    psum_block_kernel<<<NB, 256, 0, stream>>>(deg, iscan, bsum);
    scan_bsum_kernel<<<1, 64, 0, stream>>>(bsum, ebase, rowptr);
    finalize_rowptr_kernel<<<blksN, 256, 0, stream>>>(deg, iscan, ebase, rowptr);
    hipMemcpyAsync(cursor, rowptr, Nn * sizeof(int), hipMemcpyDeviceToDevice, stream);
    fill_eid_kernel<<<blksE, 256, 0, stream>>>(edge_index, cursor, eid, esrc);
    gather_feat_kernel<F1c><<<(int)(((long)Ee * F1c + 255) / 256), 256, 0, stream>>>(
        feature1, eid, featS1);
    gather_feat_kernel<6><<<(int)(((long)Ee * 6 + 255) / 256), 256, 0, stream>>>(
        feature2, eid, featS2);

    hipMemsetAsync(G1, 0, 240 * sizeof(float), stream);
    gram_kernel<F1c><<<240, 256, 0, stream>>>(feature1, G1, s1);
    gram_kernel<6><<<240, 256, 0, stream>>>(feature2, G2, s2);
    edge_bnparams_kernel<<<8, 64, 0, stream>>>(G1, s1, G2, s2,
                                               f1_w1, f1_b1, f1_g, f1_be,
                                               f2_w1, f2_b1, f2_g, f2_be,
                                               (float)Ee, scsAll, shsAll);

    auto wcv = [&](const float* src, ushortt* dh, int nmat, int K,
                   long dstMS, int kOff, long srcMS) {
        long tot = (long)nmat * 256 * K;
        wconv_kernel<<<(int)((tot + 255) / 256), 256, 0, stream>>>(src, dh, nmat, K,
                                                                   dstMS, kOff, srcMS);
    };
    wcv(linx_w, linxW, 4, 256, 65536, 0, 65536);
    wcv(c1_rel_w,  convW,          4, 256, 262144, 0,   65536);
    wcv(c1_root_w, convW,          4, 256, 262144, 256, 65536);
    wcv(c2_rel_w,  convW + 131072, 4, 256, 262144, 0,   65536);
    wcv(c2_root_w, convW + 131072, 4, 256, 262144, 256, 65536);
    wcv(cat_w, catW, 4, 512, 131072, 0, 131072);
    wcv(lins_w, linsW, 12, 256, 65536, 0, 65536);
    wcv(fin_w, finW, 4, 256, 65536, 0, 65536);
    wcv(f1_w2, fw2W,         4, 64, 32768, 0, 16384);
    wcv(f2_w2, fw2W + 16384, 4, 64, 32768, 0, 16384);

    dim3 gN(2, (Nn + 127) / 128);   // x = col-half (fastest) -> A-row L2 reuse

    for (int l = 0; l < Lc; l++) {
        // T = x @ linx_w + b -> B1 (fp16); xl = relu(BN(T)) -> X
        bgemm_kernel<<<gN, 256, 0, stream>>>(X, 256, nullptr, 0,
                                             linxW + (size_t)l * 65536,
                                             linx_b + l * Hh, nullptr, nullptr, B1,
                                             Nn, 256, 256, 0, 0);
        colstats_part_kernel<<<CSB, 256, 0, stream>>>(B1, tot4, part);
        colstats_reduce_kernel<<<2, 256, 0, stream>>>(part, colsum, colsq);
        bn_relu_h_kernel<<<blks4, 256, 0, stream>>>(B1, X, colsum, colsq,
                                                    linx_g + l * Hh, linx_be + l * Hh,
                                                    1.f / Nn, tot4);

        for (int br = 0; br < 2; br++) {
            const float* fw1 = br == 0 ? f1_w1 + (size_t)l * F1c * Mm : f2_w1 + (size_t)l * 6 * Mm;
            const float* fb2 = br == 0 ? f1_b2 + l * Hh : f2_b2 + l * Hh;
            const float* relb = br == 0 ? c1_rel_b + l * Hh : c2_rel_b + l * Hh;
            ushortt* fw2t = fw2W + (size_t)l * 32768 + (br ? 16384 : 0);
            ushortt* cvt  = convW + (size_t)l * 262144 + (br ? 131072 : 0);
            ushortt* hbr = br == 0 ? B3 : B2;
            const float* scsP = scsAll + (l * 2 + br) * 64;
            const float* shsP = shsAll + (l * 2 + br) * 64;

            for (int c0 = 0; c0 < Ee; c0 += CE) {
                int ec = Ee - c0 < CE ? Ee - c0 : CE;
                dim3 gc(2, (ec + 127) / 128);
                if (br == 0)
                    edge_gemm_kernel<F1c><<<gc, 256, 0, stream>>>(
                        featS1, fw1, scsP, shsP, fw2t, fb2, Wcb, c0, ec);
                else
                    edge_gemm_kernel<6><<<gc, 256, 0, stream>>>(
                        featS2, fw1, scsP, shsP, fw2t, fb2, Wcb, c0, ec);
                gather_agg_kernel<<<(Nn * 64 + 255) / 256, 256, 0, stream>>>(
                    rowptr, esrc, Wcb, X, aggF, single ? aggH : nullptr,
                    c0, c0 + ec, c0 == 0 ? 1 : 0);
            }
            // h_br = relu(agg @ rel_w + xl @ root_w + rel_b)
            if (single)
                bgemm_kernel<<<gN, 256, 0, stream>>>(aggH, 256, X, 256, cvt,
                                                     relb, nullptr, nullptr, hbr,
                                                     Nn, 256, 512, 1, 0);
            else
                bgemm_kernel<<<gN, 256, 0, stream>>>(aggF, 256, X, 256, cvt,
                                                     relb, nullptr, nullptr, hbr,
                                                     Nn, 256, 512, 1, 1);
        }

        // h = relu([h1,h2] @ cat_w + cat_b) + xl -> B1
        bgemm_kernel<<<gN, 256, 0, stream>>>(B3, 256, B2, 256,
                                             catW + (size_t)l * 131072,
                                             cat_b + l * Hh, X, nullptr, B1,
                                             Nn, 256, 512, 1, 0);
        // residual linears: B1 <-> B2
        ushortt* cur = B1; ushortt* oth = B2;
        for (int k = 0; k < NLc; k++) {
            bgemm_kernel<<<gN, 256, 0, stream>>>(cur, 256, nullptr, 0,
                                                 linsW + ((size_t)l * NLc + k) * 65536,
                                                 lins_b + ((size_t)l * NLc + k) * Hh, cur,
                                                 nullptr, oth, Nn, 256, 256, 1, 0);
            ushortt* t = cur; cur = oth; oth = t;
        }
        // cur == B2. Fused GraphNorm: cur -> oth (one read + one write)
        gn_fused_kernel<<<Gc, 256, 0, stream>>>(cur, gstart, gn_ms + l * Hh,
                                                gn_w + l * Hh, gn_b + l * Hh, oth);
        // x_next = h @ fin_w + fin_b
        bgemm_kernel<<<gN, 256, 0, stream>>>(oth, 256, nullptr, 0,
                                             finW + (size_t)l * 65536,
                                             fin_b + l * Hh, nullptr,
                                             (l == Lc - 1) ? (float*)d_out : nullptr,
                                             (l == Lc - 1) ? nullptr : X,
                                             Nn, 256, 256, 0, 0);
    }
}